// Round 1
// baseline (1578.926 us; speedup 1.0000x reference)
//
#include <hip/hip_runtime.h>
#include <cstddef>

#define HW   50176
#define NPIX 100352
#define IW   224

// ---------------------------------------------------------------------------
// conv 3x3 SAME, NCHW. one pixel per thread, COB output channels per thread.
// weights read with wave-uniform indices -> compiler emits scalar loads.
// ---------------------------------------------------------------------------
template<int COB>
__global__ __launch_bounds__(256) void conv3x3_k(
    const float* __restrict__ in, const float* __restrict__ w,
    const float* __restrict__ bias, float* __restrict__ out,
    int Cin, int Cout, int act)
{
    int pix = blockIdx.x * 256 + threadIdx.x;   // HW = 196*256 exactly
    int co0 = blockIdx.y * COB;
    int b   = blockIdx.z;
    int y  = pix / IW;
    int xx = pix - y * IW;

    float acc[COB];
#pragma unroll
    for (int c = 0; c < COB; c++) acc[c] = bias[co0 + c];

    const float* wb = w + (size_t)co0 * Cin * 9;

    for (int ci = 0; ci < Cin; ci++) {
        const float* ip = in + ((size_t)(b * Cin + ci)) * HW;
        float v[9];
#pragma unroll
        for (int ky = 0; ky < 3; ky++) {
            int yy = y + ky - 1;
#pragma unroll
            for (int kx = 0; kx < 3; kx++) {
                int xc = xx + kx - 1;
                float t = 0.f;
                if ((unsigned)yy < (unsigned)IW && (unsigned)xc < (unsigned)IW)
                    t = ip[yy * IW + xc];
                v[ky * 3 + kx] = t;
            }
        }
#pragma unroll
        for (int c = 0; c < COB; c++) {
            const float* wp = wb + (size_t)c * Cin * 9 + ci * 9;
#pragma unroll
            for (int k = 0; k < 9; k++) acc[c] = fmaf(v[k], wp[k], acc[c]);
        }
    }

#pragma unroll
    for (int c = 0; c < COB; c++) {
        float r = acc[c];
        if (act == 1) r = fmaxf(r, 0.f);
        else if (act == 2) r = 1.f / (1.f + __expf(-r));
        out[((size_t)(b * Cout + co0 + c)) * HW + pix] = r;
    }
}

// ---------------------------------------------------------------------------
// transpose NCHW (64ch) -> [row = b*HW + pix][64] and back
// ---------------------------------------------------------------------------
__global__ __launch_bounds__(256) void nchw2ne_k(const float* __restrict__ in,
                                                 float* __restrict__ out)
{
    __shared__ float t[64][65];
    int b  = blockIdx.z;
    int p0 = blockIdx.x * 64;
    for (int idx = threadIdx.x; idx < 4096; idx += 256) {
        int c = idx >> 6, p = idx & 63;
        t[c][p] = in[((size_t)(b * 64 + c)) * HW + p0 + p];
    }
    __syncthreads();
    for (int idx = threadIdx.x; idx < 4096; idx += 256) {
        int p = idx >> 6, c = idx & 63;
        out[((size_t)(b * HW + p0 + p)) * 64 + c] = t[c][p];
    }
}

__global__ __launch_bounds__(256) void ne2nchw_k(const float* __restrict__ in,
                                                 float* __restrict__ out)
{
    __shared__ float t[64][65];
    int b  = blockIdx.z;
    int p0 = blockIdx.x * 64;
    for (int idx = threadIdx.x; idx < 4096; idx += 256) {
        int p = idx >> 6, c = idx & 63;
        t[c][p] = in[((size_t)(b * HW + p0 + p)) * 64 + c];
    }
    __syncthreads();
    for (int idx = threadIdx.x; idx < 4096; idx += 256) {
        int c = idx >> 6, p = idx & 63;
        out[((size_t)(b * 64 + c)) * HW + p0 + p] = t[c][p];
    }
}

// ---------------------------------------------------------------------------
// generic GEMM: C[row, col0+col] = sum_e A[row,e] * W[col0+col, e] + bias
// A: [NPIX,64], W: [Ncols,64] row-major. 64x64 tile per block, 4x4 microtile.
// ---------------------------------------------------------------------------
__global__ __launch_bounds__(256) void gemm64_k(
    const float* __restrict__ A, const float* __restrict__ W,
    const float* __restrict__ bias, float* __restrict__ C, int ldc, int act)
{
    __shared__ __align__(16) float At[64 * 68];  // At[e][row]
    __shared__ __align__(16) float Wl[64 * 68];  // Wl[e][col]
    int row0 = blockIdx.x * 64, col0 = blockIdx.y * 64;
    int tid = threadIdx.x;
    int ty = tid >> 4, tx = tid & 15;

    for (int idx = tid; idx < 4096; idx += 256) {
        int r = idx >> 6, e = idx & 63;
        At[e * 68 + r] = A[((size_t)(row0 + r)) * 64 + e];
        Wl[e * 68 + r] = W[((size_t)(col0 + r)) * 64 + e];  // r plays "col"
    }
    __syncthreads();

    float acc[4][4] = {};
    for (int e = 0; e < 64; e++) {
        float4 a = *reinterpret_cast<const float4*>(&At[e * 68 + 4 * ty]);
        float4 b = *reinterpret_cast<const float4*>(&Wl[e * 68 + 4 * tx]);
        float av[4] = {a.x, a.y, a.z, a.w};
        float bv[4] = {b.x, b.y, b.z, b.w};
#pragma unroll
        for (int i = 0; i < 4; i++)
#pragma unroll
            for (int j = 0; j < 4; j++)
                acc[i][j] = fmaf(av[i], bv[j], acc[i][j]);
    }

#pragma unroll
    for (int i = 0; i < 4; i++) {
        int row = row0 + 4 * ty + i;
        float4 o;
        float* po = (float*)&o;
#pragma unroll
        for (int j = 0; j < 4; j++) {
            float r = acc[i][j] + bias[col0 + 4 * tx + j];
            if (act == 1) r = fmaxf(r, 0.f);
            po[j] = r;
        }
        *reinterpret_cast<float4*>(&C[(size_t)row * ldc + col0 + 4 * tx]) = o;
    }
}

// ---------------------------------------------------------------------------
// attention: per (n, h). S=2 -> 2x2 scores, softmax over t, weighted V.
// ---------------------------------------------------------------------------
__global__ __launch_bounds__(256) void attn_k(const float* __restrict__ qkv,
                                              float* __restrict__ out)
{
    int gid = blockIdx.x * 256 + threadIdx.x;  // < HW*4
    int n = gid >> 2, h = gid & 3;
    const float* r0 = qkv + (size_t)n * 192 + h * 16;          // s=0
    const float* r1 = qkv + ((size_t)HW + n) * 192 + h * 16;   // s=1

    float s00 = 0, s01 = 0, s10 = 0, s11 = 0;
#pragma unroll
    for (int d = 0; d < 16; d += 4) {
        float4 q0 = *reinterpret_cast<const float4*>(r0 + d);
        float4 k0 = *reinterpret_cast<const float4*>(r0 + 64 + d);
        float4 q1 = *reinterpret_cast<const float4*>(r1 + d);
        float4 k1 = *reinterpret_cast<const float4*>(r1 + 64 + d);
        s00 += q0.x * k0.x + q0.y * k0.y + q0.z * k0.z + q0.w * k0.w;
        s01 += q0.x * k1.x + q0.y * k1.y + q0.z * k1.z + q0.w * k1.w;
        s10 += q1.x * k0.x + q1.y * k0.y + q1.z * k0.z + q1.w * k0.w;
        s11 += q1.x * k1.x + q1.y * k1.y + q1.z * k1.z + q1.w * k1.w;
    }
    s00 *= 0.25f; s01 *= 0.25f; s10 *= 0.25f; s11 *= 0.25f;

    float m0 = fmaxf(s00, s01);
    float e00 = __expf(s00 - m0), e01 = __expf(s01 - m0);
    float i0 = 1.f / (e00 + e01);
    float p00 = e00 * i0, p01 = e01 * i0;

    float m1 = fmaxf(s10, s11);
    float e10 = __expf(s10 - m1), e11 = __expf(s11 - m1);
    float i1 = 1.f / (e10 + e11);
    float p10 = e10 * i1, p11 = e11 * i1;

    float* o0 = out + (size_t)n * 64 + h * 16;
    float* o1 = out + ((size_t)HW + n) * 64 + h * 16;
#pragma unroll
    for (int d = 0; d < 16; d += 4) {
        float4 v0 = *reinterpret_cast<const float4*>(r0 + 128 + d);
        float4 v1 = *reinterpret_cast<const float4*>(r1 + 128 + d);
        float4 a0, a1;
        a0.x = p00 * v0.x + p01 * v1.x;  a0.y = p00 * v0.y + p01 * v1.y;
        a0.z = p00 * v0.z + p01 * v1.z;  a0.w = p00 * v0.w + p01 * v1.w;
        a1.x = p10 * v0.x + p11 * v1.x;  a1.y = p10 * v0.y + p11 * v1.y;
        a1.z = p10 * v0.z + p11 * v1.z;  a1.w = p10 * v0.w + p11 * v1.w;
        *reinterpret_cast<float4*>(o0 + d) = a0;
        *reinterpret_cast<float4*>(o1 + d) = a1;
    }
}

// ---------------------------------------------------------------------------
// layernorm over E=64: out = g * (a+b - mu) * rsqrt(var+eps) + be
// one wave (64 lanes) per row, 4 rows per block.
// ---------------------------------------------------------------------------
__global__ __launch_bounds__(256) void ln_k(const float* __restrict__ A,
                                            const float* __restrict__ Bv,
                                            const float* __restrict__ g,
                                            const float* __restrict__ be,
                                            float* __restrict__ out)
{
    int row = blockIdx.x * 4 + (threadIdx.x >> 6);
    int e = threadIdx.x & 63;
    size_t idx = (size_t)row * 64 + e;
    float x = A[idx] + Bv[idx];
    float s = x;
#pragma unroll
    for (int o = 32; o; o >>= 1) s += __shfl_xor(s, o, 64);
    float mu = s * 0.015625f;
    float xc = x - mu;
    float vv = xc * xc;
#pragma unroll
    for (int o = 32; o; o >>= 1) vv += __shfl_xor(vv, o, 64);
    vv *= 0.015625f;
    out[idx] = g[e] * xc * rsqrtf(vv + 1e-5f) + be[e];
}

// ---------------------------------------------------------------------------
// fused FFN: out[row,:64] = relu(t1[row,:] @ W1^T + b1) @ W2^T + b2
// 64 rows/block; hidden (2048) chunked by 64; hidden never hits global.
// ---------------------------------------------------------------------------
__global__ __launch_bounds__(256) void ffn_k(
    const float* __restrict__ T1, const float* __restrict__ W1,
    const float* __restrict__ B1, const float* __restrict__ W2,
    const float* __restrict__ B2, float* __restrict__ Out)
{
    __shared__ __align__(16) float At[64 * 68];   // [e][row]
    __shared__ __align__(16) float Wl[64 * 68];   // [e][j]
    __shared__ __align__(16) float Ht[64 * 68];   // [j][row]
    __shared__ __align__(16) float W2l[64 * 68];  // [j][e2]
    int tid = threadIdx.x;
    int row0 = blockIdx.x * 64;
    int ty = tid >> 4, tx = tid & 15;

    for (int idx = tid; idx < 4096; idx += 256) {
        int r = idx >> 6, e = idx & 63;
        At[e * 68 + r] = T1[((size_t)(row0 + r)) * 64 + e];
    }

    float acc2[4][4] = {};

    for (int c = 0; c < 32; c++) {
        __syncthreads();  // previous iter done reading Wl/W2l/Ht (covers At at c=0)
        for (int idx = tid; idx < 4096; idx += 256) {
            int a_ = idx >> 6, b_ = idx & 63;
            Wl [b_ * 68 + a_] = W1[((size_t)(c * 64 + a_)) * 64 + b_];  // [e][j]
            W2l[b_ * 68 + a_] = W2[(size_t)a_ * 2048 + c * 64 + b_];    // [j][e2]
        }
        __syncthreads();

        // phase 1: h[row, j] = relu(b1 + sum_e t1[row,e] * W1[j,e])
        float hacc[4][4] = {};
        for (int e = 0; e < 64; e++) {
            float4 a = *reinterpret_cast<const float4*>(&At[e * 68 + 4 * ty]);
            float4 b = *reinterpret_cast<const float4*>(&Wl[e * 68 + 4 * tx]);
            float av[4] = {a.x, a.y, a.z, a.w};
            float bv[4] = {b.x, b.y, b.z, b.w};
#pragma unroll
            for (int i = 0; i < 4; i++)
#pragma unroll
                for (int j = 0; j < 4; j++)
                    hacc[i][j] = fmaf(av[i], bv[j], hacc[i][j]);
        }
#pragma unroll
        for (int j = 0; j < 4; j++) {
            float bj = B1[c * 64 + 4 * tx + j];
            float4 hv;
            hv.x = fmaxf(hacc[0][j] + bj, 0.f);
            hv.y = fmaxf(hacc[1][j] + bj, 0.f);
            hv.z = fmaxf(hacc[2][j] + bj, 0.f);
            hv.w = fmaxf(hacc[3][j] + bj, 0.f);
            *reinterpret_cast<float4*>(&Ht[(4 * tx + j) * 68 + 4 * ty]) = hv;
        }
        __syncthreads();

        // phase 2: out[row, e2] += sum_j h[row,j] * W2[e2, jglob]
        for (int j = 0; j < 64; j++) {
            float4 a = *reinterpret_cast<const float4*>(&Ht[j * 68 + 4 * ty]);
            float4 b = *reinterpret_cast<const float4*>(&W2l[j * 68 + 4 * tx]);
            float av[4] = {a.x, a.y, a.z, a.w};
            float bv[4] = {b.x, b.y, b.z, b.w};
#pragma unroll
            for (int i = 0; i < 4; i++)
#pragma unroll
                for (int jj = 0; jj < 4; jj++)
                    acc2[i][jj] = fmaf(av[i], bv[jj], acc2[i][jj]);
        }
    }

#pragma unroll
    for (int i = 0; i < 4; i++) {
        int row = row0 + 4 * ty + i;
        float4 o;
        o.x = acc2[i][0] + B2[4 * tx + 0];
        o.y = acc2[i][1] + B2[4 * tx + 1];
        o.z = acc2[i][2] + B2[4 * tx + 2];
        o.w = acc2[i][3] + B2[4 * tx + 3];
        *reinterpret_cast<float4*>(&Out[(size_t)row * 64 + 4 * tx]) = o;
    }
}

// ---------------------------------------------------------------------------
// s = sum over 3 input channels of x
// ---------------------------------------------------------------------------
__global__ __launch_bounds__(256) void ssum_k(const float* __restrict__ x,
                                              float* __restrict__ s)
{
    int gid = blockIdx.x * 256 + threadIdx.x;  // < NPIX
    int b = gid / HW;
    int p = gid - b * HW;
    const float* xp = x + (size_t)b * 3 * HW + p;
    s[gid] = xp[0] + xp[HW] + xp[2 * HW];
}

// ---------------------------------------------------------------------------
// KPN fuse: fused[b,y,x] = sum_{u,v} f[b,u*3+v,y,x] * s_pad[b,y+u-1,x+v-1]
// ---------------------------------------------------------------------------
__global__ __launch_bounds__(256) void kpn_k(const float* __restrict__ f,
                                             const float* __restrict__ s,
                                             float* __restrict__ out)
{
    int gid = blockIdx.x * 256 + threadIdx.x;  // < NPIX
    int b = gid / HW;
    int p = gid - b * HW;
    int y = p / IW, x = p - y * IW;
    const float* fp = f + (size_t)b * 9 * HW + p;
    const float* sp = s + (size_t)b * HW;
    float acc = 0.f;
#pragma unroll
    for (int u = 0; u < 3; u++) {
        int yy = y + u - 1;
        if ((unsigned)yy >= (unsigned)IW) continue;
#pragma unroll
        for (int v = 0; v < 3; v++) {
            int xx = x + v - 1;
            if ((unsigned)xx >= (unsigned)IW) continue;
            acc += fp[(size_t)(u * 3 + v) * HW] * sp[yy * IW + xx];
        }
    }
    out[gid] = acc;
}

// ---------------------------------------------------------------------------
extern "C" void kernel_launch(void* const* d_in, const int* in_sizes, int n_in,
                              void* d_out, int out_size, void* d_ws, size_t ws_size,
                              hipStream_t stream)
{
    const float* x      = (const float*)d_in[0];
    const float* enc_w1 = (const float*)d_in[1];
    const float* enc_b1 = (const float*)d_in[2];
    const float* enc_w2 = (const float*)d_in[3];
    const float* enc_b2 = (const float*)d_in[4];
    const float* in_w   = (const float*)d_in[5];
    const float* in_b   = (const float*)d_in[6];
    const float* out_w  = (const float*)d_in[7];
    const float* out_b  = (const float*)d_in[8];
    const float* ln1_g  = (const float*)d_in[9];
    const float* ln1_b  = (const float*)d_in[10];
    const float* ffn_w1 = (const float*)d_in[11];
    const float* ffn_b1 = (const float*)d_in[12];
    const float* ffn_w2 = (const float*)d_in[13];
    const float* ffn_b2 = (const float*)d_in[14];
    const float* ln2_g  = (const float*)d_in[15];
    const float* ln2_b  = (const float*)d_in[16];
    const float* sf_w1  = (const float*)d_in[17];
    const float* sf_b1  = (const float*)d_in[18];
    const float* sf_w2  = (const float*)d_in[19];
    const float* sf_b2  = (const float*)d_in[20];
    const float* dec_w1 = (const float*)d_in[21];
    const float* dec_b1 = (const float*)d_in[22];
    const float* dec_w2 = (const float*)d_in[23];
    const float* dec_b2 = (const float*)d_in[24];

    float* ws = (float*)d_ws;
    const size_t SZ = (size_t)NPIX * 64;    // 6.42M floats = 25.7 MB
    float* bufA = ws;                        // total WS use: 6*SZ*4 = 154 MB
    float* bufB = ws + SZ;
    float* bufC = ws + 2 * SZ;
    float* bufD = ws + 3 * SZ;               // qkv needs 3*SZ

    // encoder convs
    conv3x3_k<4><<<dim3(196, 16, 2), 256, 0, stream>>>(x,    enc_w1, enc_b1, bufA, 3,  64, 1);
    conv3x3_k<4><<<dim3(196, 16, 2), 256, 0, stream>>>(bufA, enc_w2, enc_b2, bufB, 64, 64, 1);
    // NCHW -> [row][64]
    nchw2ne_k<<<dim3(784, 1, 2), 256, 0, stream>>>(bufB, bufC);
    // qkv projection [NPIX,64] @ [192,64]^T
    gemm64_k<<<dim3(1568, 3), 256, 0, stream>>>(bufC, in_w, in_b, bufD, 192, 0);
    // attention (S=2 per pixel/head)
    attn_k<<<784, 256, 0, stream>>>(bufD, bufA);
    // out projection
    gemm64_k<<<dim3(1568, 1), 256, 0, stream>>>(bufA, out_w, out_b, bufB, 64, 0);
    // t1 = LN(t + proj)
    ln_k<<<25088, 256, 0, stream>>>(bufC, bufB, ln1_g, ln1_b, bufA);
    // fused FFN
    ffn_k<<<1568, 256, 0, stream>>>(bufA, ffn_w1, ffn_b1, ffn_w2, ffn_b2, bufB);
    // t2 = LN(t1 + ff)
    ln_k<<<25088, 256, 0, stream>>>(bufA, bufB, ln2_g, ln2_b, bufC);
    // back to NCHW
    ne2nchw_k<<<dim3(784, 1, 2), 256, 0, stream>>>(bufC, bufD);
    // filter-prediction convs (NO relu between them)
    conv3x3_k<4><<<dim3(196, 8, 2), 256, 0, stream>>>(bufD, sf_w1, sf_b1, bufA, 64, 32, 0);
    conv3x3_k<3><<<dim3(196, 3, 2), 256, 0, stream>>>(bufA, sf_w2, sf_b2, bufB, 32, 9,  0);
    // channel-sum of input, then per-pixel 3x3 dynamic filter
    ssum_k<<<392, 256, 0, stream>>>(x, bufC);
    kpn_k<<<392, 256, 0, stream>>>(bufB, bufC, bufA);
    // decoder
    conv3x3_k<4><<<dim3(196, 16, 2), 256, 0, stream>>>(bufA, dec_w1, dec_b1, bufC, 1,  64, 1);
    conv3x3_k<1><<<dim3(196, 1, 2), 256, 0, stream>>>(bufC, dec_w2, dec_b2, (float*)d_out, 64, 1, 2);
}

// Round 2
// 862.888 us; speedup vs baseline: 1.8298x; 1.8298x over previous
//
#include <hip/hip_runtime.h>
#include <hip/hip_bf16.h>
#include <cstddef>

#define HW   50176
#define NPIX 100352
#define IW   224

typedef unsigned short ushort_t;
typedef __attribute__((ext_vector_type(8))) short bf16x8;
typedef __attribute__((ext_vector_type(8))) unsigned short ushort8;
typedef __attribute__((ext_vector_type(4))) float f32x4;

__device__ inline ushort_t f2bf(float f) {
    __hip_bfloat16 h = __float2bfloat16(f);
    return __builtin_bit_cast(ushort_t, h);
}
__device__ inline float bf2f(ushort_t u) {
    return __uint_as_float(((unsigned)u) << 16);
}
__device__ inline bf16x8 ldg8(const ushort_t* p) {
    return *reinterpret_cast<const bf16x8*>(p);
}
__device__ inline void b2f8(const ushort_t* p, float* f) {
    ushort8 v = *reinterpret_cast<const ushort8*>(p);
#pragma unroll
    for (int i = 0; i < 8; i++) f[i] = bf2f(v[i]);
}

// ---------------------------------------------------------------------------
// fp32 -> bf16 conversion (weights, once per launch)
// ---------------------------------------------------------------------------
__global__ __launch_bounds__(256) void f2bf_k(const float* __restrict__ in,
                                              ushort_t* __restrict__ out, int n)
{
    int i = blockIdx.x * 256 + threadIdx.x;
    if (i < n) out[i] = f2bf(in[i]);
}

// ---------------------------------------------------------------------------
// conv 3x3 SAME, NCHW. one pixel per thread, COB output channels per thread.
// ---------------------------------------------------------------------------
template<int COB>
__global__ __launch_bounds__(256) void conv3x3_k(
    const float* __restrict__ in, const float* __restrict__ w,
    const float* __restrict__ bias, float* __restrict__ out,
    int Cin, int Cout, int act)
{
    int pix = blockIdx.x * 256 + threadIdx.x;
    int co0 = blockIdx.y * COB;
    int b   = blockIdx.z;
    int y  = pix / IW;
    int xx = pix - y * IW;

    float acc[COB];
#pragma unroll
    for (int c = 0; c < COB; c++) acc[c] = bias[co0 + c];

    const float* wb = w + (size_t)co0 * Cin * 9;

    for (int ci = 0; ci < Cin; ci++) {
        const float* ip = in + ((size_t)(b * Cin + ci)) * HW;
        float v[9];
#pragma unroll
        for (int ky = 0; ky < 3; ky++) {
            int yy = y + ky - 1;
#pragma unroll
            for (int kx = 0; kx < 3; kx++) {
                int xc = xx + kx - 1;
                float t = 0.f;
                if ((unsigned)yy < (unsigned)IW && (unsigned)xc < (unsigned)IW)
                    t = ip[yy * IW + xc];
                v[ky * 3 + kx] = t;
            }
        }
#pragma unroll
        for (int c = 0; c < COB; c++) {
            const float* wp = wb + (size_t)c * Cin * 9 + ci * 9;
#pragma unroll
            for (int k = 0; k < 9; k++) acc[c] = fmaf(v[k], wp[k], acc[c]);
        }
    }

#pragma unroll
    for (int c = 0; c < COB; c++) {
        float r = acc[c];
        if (act == 1) r = fmaxf(r, 0.f);
        else if (act == 2) r = 1.f / (1.f + __expf(-r));
        out[((size_t)(b * Cout + co0 + c)) * HW + pix] = r;
    }
}

// ---------------------------------------------------------------------------
// NCHW (64ch) -> [row][64], fp32 + bf16 outputs
// ---------------------------------------------------------------------------
__global__ __launch_bounds__(256) void nchw2ne_k(const float* __restrict__ in,
                                                 float* __restrict__ out,
                                                 ushort_t* __restrict__ outb)
{
    __shared__ float t[64][65];
    int b  = blockIdx.z;
    int p0 = blockIdx.x * 64;
    for (int idx = threadIdx.x; idx < 4096; idx += 256) {
        int c = idx >> 6, p = idx & 63;
        t[c][p] = in[((size_t)(b * 64 + c)) * HW + p0 + p];
    }
    __syncthreads();
    for (int idx = threadIdx.x; idx < 4096; idx += 256) {
        int p = idx >> 6, c = idx & 63;
        float v = t[c][p];
        size_t o = ((size_t)(b * HW + p0 + p)) * 64 + c;
        out[o]  = v;
        outb[o] = f2bf(v);
    }
}

__global__ __launch_bounds__(256) void ne2nchw_k(const float* __restrict__ in,
                                                 float* __restrict__ out)
{
    __shared__ float t[64][65];
    int b  = blockIdx.z;
    int p0 = blockIdx.x * 64;
    for (int idx = threadIdx.x; idx < 4096; idx += 256) {
        int p = idx >> 6, c = idx & 63;
        t[c][p] = in[((size_t)(b * HW + p0 + p)) * 64 + c];
    }
    __syncthreads();
    for (int idx = threadIdx.x; idx < 4096; idx += 256) {
        int c = idx >> 6, p = idx & 63;
        out[((size_t)(b * 64 + c)) * HW + p0 + p] = t[c][p];
    }
}

// ---------------------------------------------------------------------------
// MFMA GEMM: C[row, col] = sum_e A[row,e]*W[col,e] + bias[col]
// A bf16 [M][64], W bf16 [Ncols][64]. 64x64 tile/block, wave = 16 rows.
// Fragment layouts (16x16x32 bf16, verified m89/m120):
//   A: m=lane&15, k=(lane>>4)*8+j (j contiguous)    -> 16B global load
//   B: n=lane&15, k=(lane>>4)*8+j                   -> 16B global load
//   D: col=lane&15, row=(lane>>4)*4+reg
// ---------------------------------------------------------------------------
template<bool OBF16>
__global__ __launch_bounds__(256) void gemmA64_mfma_k(
    const ushort_t* __restrict__ Ab, const ushort_t* __restrict__ Wb,
    const float* __restrict__ bias, void* __restrict__ Cout, int ldc)
{
    int tid = threadIdx.x, wave = tid >> 6, lane = tid & 63;
    int lm = lane & 15, quad = lane >> 4;
    int row0 = blockIdx.x * 64 + wave * 16;
    int col0 = blockIdx.y * 64;

    bf16x8 a[2];
#pragma unroll
    for (int ks = 0; ks < 2; ks++)
        a[ks] = ldg8(Ab + (size_t)(row0 + lm) * 64 + ks * 32 + quad * 8);

    f32x4 acc[4] = {};
#pragma unroll
    for (int nt = 0; nt < 4; nt++)
#pragma unroll
        for (int ks = 0; ks < 2; ks++) {
            bf16x8 b = ldg8(Wb + (size_t)(col0 + nt * 16 + lm) * 64 + ks * 32 + quad * 8);
            acc[nt] = __builtin_amdgcn_mfma_f32_16x16x32_bf16(a[ks], b, acc[nt], 0, 0, 0);
        }

#pragma unroll
    for (int nt = 0; nt < 4; nt++) {
        float bv = bias[col0 + nt * 16 + lm];
#pragma unroll
        for (int r = 0; r < 4; r++) {
            float v = acc[nt][r] + bv;
            size_t o = (size_t)(row0 + quad * 4 + r) * ldc + col0 + nt * 16 + lm;
            if (OBF16) ((ushort_t*)Cout)[o] = f2bf(v);
            else       ((float*)Cout)[o] = v;
        }
    }
}

// ---------------------------------------------------------------------------
// attention: per (n, h). S=2 -> 2x2 scores. bf16 in (qkv [row][192]), bf16 out.
// ---------------------------------------------------------------------------
__global__ __launch_bounds__(256) void attn_k(const ushort_t* __restrict__ qkv,
                                              ushort_t* __restrict__ out)
{
    int gid = blockIdx.x * 256 + threadIdx.x;  // < HW*4
    int n = gid >> 2, h = gid & 3;
    const ushort_t* r0 = qkv + (size_t)n * 192 + h * 16;
    const ushort_t* r1 = qkv + ((size_t)HW + n) * 192 + h * 16;

    float q0[16], k0[16], v0[16], q1[16], k1[16], v1[16];
    b2f8(r0,       q0); b2f8(r0 + 8,   q0 + 8);
    b2f8(r0 + 64,  k0); b2f8(r0 + 72,  k0 + 8);
    b2f8(r0 + 128, v0); b2f8(r0 + 136, v0 + 8);
    b2f8(r1,       q1); b2f8(r1 + 8,   q1 + 8);
    b2f8(r1 + 64,  k1); b2f8(r1 + 72,  k1 + 8);
    b2f8(r1 + 128, v1); b2f8(r1 + 136, v1 + 8);

    float s00 = 0, s01 = 0, s10 = 0, s11 = 0;
#pragma unroll
    for (int d = 0; d < 16; d++) {
        s00 += q0[d] * k0[d]; s01 += q0[d] * k1[d];
        s10 += q1[d] * k0[d]; s11 += q1[d] * k1[d];
    }
    s00 *= 0.25f; s01 *= 0.25f; s10 *= 0.25f; s11 *= 0.25f;

    float m0 = fmaxf(s00, s01);
    float e00 = __expf(s00 - m0), e01 = __expf(s01 - m0);
    float i0 = 1.f / (e00 + e01);
    float p00 = e00 * i0, p01 = e01 * i0;

    float m1 = fmaxf(s10, s11);
    float e10 = __expf(s10 - m1), e11 = __expf(s11 - m1);
    float i1 = 1.f / (e10 + e11);
    float p10 = e10 * i1, p11 = e11 * i1;

    ushort_t* o0 = out + (size_t)n * 64 + h * 16;
    ushort_t* o1 = out + ((size_t)HW + n) * 64 + h * 16;
#pragma unroll
    for (int c = 0; c < 2; c++) {
        ushort8 a0v, a1v;
#pragma unroll
        for (int i = 0; i < 8; i++) {
            int d = c * 8 + i;
            a0v[i] = f2bf(p00 * v0[d] + p01 * v1[d]);
            a1v[i] = f2bf(p10 * v0[d] + p11 * v1[d]);
        }
        *reinterpret_cast<ushort8*>(o0 + c * 8) = a0v;
        *reinterpret_cast<ushort8*>(o1 + c * 8) = a1v;
    }
}

// ---------------------------------------------------------------------------
// layernorm over E=64. fp32 out + optional bf16 out.
// ---------------------------------------------------------------------------
__global__ __launch_bounds__(256) void ln_k(const float* __restrict__ A,
                                            const float* __restrict__ Bv,
                                            const float* __restrict__ g,
                                            const float* __restrict__ be,
                                            float* __restrict__ out,
                                            ushort_t* __restrict__ ob)
{
    int row = blockIdx.x * 4 + (threadIdx.x >> 6);
    int e = threadIdx.x & 63;
    size_t idx = (size_t)row * 64 + e;
    float x = A[idx] + Bv[idx];
    float s = x;
#pragma unroll
    for (int o = 32; o; o >>= 1) s += __shfl_xor(s, o, 64);
    float mu = s * 0.015625f;
    float xc = x - mu;
    float vv = xc * xc;
#pragma unroll
    for (int o = 32; o; o >>= 1) vv += __shfl_xor(vv, o, 64);
    vv *= 0.015625f;
    float r = g[e] * xc * rsqrtf(vv + 1e-5f) + be[e];
    out[idx] = r;
    if (ob) ob[idx] = f2bf(r);
}

// ---------------------------------------------------------------------------
// fused FFN via MFMA: out = relu(T1 @ W1^T + b1) @ W2^T + b2
// 4 waves/block, 32 rows/wave (128/block). Hidden chunked by 64; chunk
// round-trips through WAVE-PRIVATE LDS (no barriers anywhere).
// W1b: [2048][64] bf16 (k=e contiguous), W2b: [64][2048] bf16 (k=j contiguous).
// ---------------------------------------------------------------------------
__global__ __launch_bounds__(256) void ffn_mfma_k(
    const ushort_t* __restrict__ T1b, const ushort_t* __restrict__ W1b,
    const float* __restrict__ B1, const ushort_t* __restrict__ W2b,
    const float* __restrict__ B2, float* __restrict__ Out)
{
    // 32 rows x 72 bf16 per wave; stride 144 B = 16B-aligned, 2-way bank alias (free)
    __shared__ ushort_t Hs[4][32 * 72];
    int tid = threadIdx.x;
    int wave = tid >> 6, lane = tid & 63;
    int lm = lane & 15, quad = lane >> 4;
    int rowbase = blockIdx.x * 128 + wave * 32;
    ushort_t* Hw = Hs[wave];

    // A1 fragments are chunk-invariant: load once
    bf16x8 A1[2][2];
#pragma unroll
    for (int mt = 0; mt < 2; mt++)
#pragma unroll
        for (int ks = 0; ks < 2; ks++)
            A1[mt][ks] = ldg8(T1b + (size_t)(rowbase + mt * 16 + lm) * 64 + ks * 32 + quad * 8);

    f32x4 acc[2][4] = {};

    for (int c = 0; c < 32; c++) {
        // ---- phase 1: H = relu(T1 @ W1chunk^T + b1) ----
        f32x4 h[2][4] = {};
#pragma unroll
        for (int nt = 0; nt < 4; nt++)
#pragma unroll
            for (int ks = 0; ks < 2; ks++) {
                bf16x8 b = ldg8(W1b + (size_t)(c * 64 + nt * 16 + lm) * 64 + ks * 32 + quad * 8);
                h[0][nt] = __builtin_amdgcn_mfma_f32_16x16x32_bf16(A1[0][ks], b, h[0][nt], 0, 0, 0);
                h[1][nt] = __builtin_amdgcn_mfma_f32_16x16x32_bf16(A1[1][ks], b, h[1][nt], 0, 0, 0);
            }
        // bias + relu + cvt -> wave-private LDS in A-operand layout
#pragma unroll
        for (int nt = 0; nt < 4; nt++) {
            float bj = B1[c * 64 + nt * 16 + lm];
#pragma unroll
            for (int mt = 0; mt < 2; mt++)
#pragma unroll
                for (int r = 0; r < 4; r++) {
                    float v = fmaxf(h[mt][nt][r] + bj, 0.f);
                    Hw[(mt * 16 + quad * 4 + r) * 72 + nt * 16 + lm] = f2bf(v);
                }
        }
        // ---- phase 2: acc += H @ W2chunk^T ----
        bf16x8 A2[2][2];
#pragma unroll
        for (int mt = 0; mt < 2; mt++)
#pragma unroll
            for (int ks = 0; ks < 2; ks++)
                A2[mt][ks] = *reinterpret_cast<bf16x8*>(&Hw[(mt * 16 + lm) * 72 + ks * 32 + quad * 8]);
#pragma unroll
        for (int nt = 0; nt < 4; nt++)
#pragma unroll
            for (int ks = 0; ks < 2; ks++) {
                bf16x8 b = ldg8(W2b + (size_t)(nt * 16 + lm) * 2048 + c * 64 + ks * 32 + quad * 8);
                acc[0][nt] = __builtin_amdgcn_mfma_f32_16x16x32_bf16(A2[0][ks], b, acc[0][nt], 0, 0, 0);
                acc[1][nt] = __builtin_amdgcn_mfma_f32_16x16x32_bf16(A2[1][ks], b, acc[1][nt], 0, 0, 0);
            }
    }

#pragma unroll
    for (int nt = 0; nt < 4; nt++) {
        float be = B2[nt * 16 + lm];
#pragma unroll
        for (int mt = 0; mt < 2; mt++)
#pragma unroll
            for (int r = 0; r < 4; r++)
                Out[(size_t)(rowbase + mt * 16 + quad * 4 + r) * 64 + nt * 16 + lm] =
                    acc[mt][nt][r] + be;
    }
}

// ---------------------------------------------------------------------------
__global__ __launch_bounds__(256) void ssum_k(const float* __restrict__ x,
                                              float* __restrict__ s)
{
    int gid = blockIdx.x * 256 + threadIdx.x;
    int b = gid / HW;
    int p = gid - b * HW;
    const float* xp = x + (size_t)b * 3 * HW + p;
    s[gid] = xp[0] + xp[HW] + xp[2 * HW];
}

__global__ __launch_bounds__(256) void kpn_k(const float* __restrict__ f,
                                             const float* __restrict__ s,
                                             float* __restrict__ out)
{
    int gid = blockIdx.x * 256 + threadIdx.x;
    int b = gid / HW;
    int p = gid - b * HW;
    int y = p / IW, x = p - y * IW;
    const float* fp = f + (size_t)b * 9 * HW + p;
    const float* sp = s + (size_t)b * HW;
    float acc = 0.f;
#pragma unroll
    for (int u = 0; u < 3; u++) {
        int yy = y + u - 1;
        if ((unsigned)yy >= (unsigned)IW) continue;
#pragma unroll
        for (int v = 0; v < 3; v++) {
            int xx = x + v - 1;
            if ((unsigned)xx >= (unsigned)IW) continue;
            acc += fp[(size_t)(u * 3 + v) * HW] * sp[yy * IW + xx];
        }
    }
    out[gid] = acc;
}

// ---------------------------------------------------------------------------
extern "C" void kernel_launch(void* const* d_in, const int* in_sizes, int n_in,
                              void* d_out, int out_size, void* d_ws, size_t ws_size,
                              hipStream_t stream)
{
    const float* x      = (const float*)d_in[0];
    const float* enc_w1 = (const float*)d_in[1];
    const float* enc_b1 = (const float*)d_in[2];
    const float* enc_w2 = (const float*)d_in[3];
    const float* enc_b2 = (const float*)d_in[4];
    const float* in_w   = (const float*)d_in[5];
    const float* in_b   = (const float*)d_in[6];
    const float* out_w  = (const float*)d_in[7];
    const float* out_b  = (const float*)d_in[8];
    const float* ln1_g  = (const float*)d_in[9];
    const float* ln1_b  = (const float*)d_in[10];
    const float* ffn_w1 = (const float*)d_in[11];
    const float* ffn_b1 = (const float*)d_in[12];
    const float* ffn_w2 = (const float*)d_in[13];
    const float* ffn_b2 = (const float*)d_in[14];
    const float* ln2_g  = (const float*)d_in[15];
    const float* ln2_b  = (const float*)d_in[16];
    const float* sf_w1  = (const float*)d_in[17];
    const float* sf_b1  = (const float*)d_in[18];
    const float* sf_w2  = (const float*)d_in[19];
    const float* sf_b2  = (const float*)d_in[20];
    const float* dec_w1 = (const float*)d_in[21];
    const float* dec_b1 = (const float*)d_in[22];
    const float* dec_w2 = (const float*)d_in[23];
    const float* dec_b2 = (const float*)d_in[24];

    float* ws = (float*)d_ws;
    const size_t SZ = (size_t)NPIX * 64;   // 6,422,528 floats

    float*    fA    = ws;                   // [0, 1SZ)
    float*    fB    = ws + SZ;              // [1, 2SZ)
    float*    fT    = ws + 2 * SZ;          // [2, 3SZ)
    ushort_t* QKVb  = (ushort_t*)(ws + 3 * SZ);            // [3, 4.5SZ)
    ushort_t* ATb   = (ushort_t*)(ws + 9 * SZ / 2);        // [4.5, 5SZ)
    ushort_t* Tb    = (ushort_t*)(ws + 5 * SZ);            // [5, 5.5SZ) also reused as T1b
    ushort_t* wu    = (ushort_t*)(ws + 11 * SZ / 2);       // weights bf16
    ushort_t* in_wb  = wu;                  // 12288
    ushort_t* out_wb = wu + 12288;          // 4096
    ushort_t* w1b    = wu + 16384;          // 131072
    ushort_t* w2b    = wu + 147456;         // 131072
    // late-stage scratch inside dead QKV region:
    float* s1out = ws + 3 * SZ;                      // NPIX*32
    float* filt  = ws + 3 * SZ + SZ / 2;             // NPIX*9
    float* sbuf  = ws + 3 * SZ + SZ / 2 + 903168;    // NPIX
    float* fused = sbuf + NPIX;                      // NPIX

    // weight conversions
    f2bf_k<<<48,  256, 0, stream>>>(in_w,   in_wb,  12288);
    f2bf_k<<<16,  256, 0, stream>>>(out_w,  out_wb, 4096);
    f2bf_k<<<512, 256, 0, stream>>>(ffn_w1, w1b,    131072);
    f2bf_k<<<512, 256, 0, stream>>>(ffn_w2, w2b,    131072);

    // encoder convs
    conv3x3_k<4><<<dim3(196, 16, 2), 256, 0, stream>>>(x,  enc_w1, enc_b1, fA, 3,  64, 1);
    conv3x3_k<4><<<dim3(196, 16, 2), 256, 0, stream>>>(fA, enc_w2, enc_b2, fB, 64, 64, 1);
    // NCHW -> [row][64] fp32 + bf16
    nchw2ne_k<<<dim3(784, 1, 2), 256, 0, stream>>>(fB, fT, Tb);
    // qkv projection (bf16 out)
    gemmA64_mfma_k<true><<<dim3(1568, 3), 256, 0, stream>>>(Tb, in_wb, in_b, QKVb, 192);
    // attention (bf16 in/out)
    attn_k<<<784, 256, 0, stream>>>(QKVb, ATb);
    // out projection (fp32 out)
    gemmA64_mfma_k<false><<<dim3(1568, 1), 256, 0, stream>>>(ATb, out_wb, out_b, fA, 64);
    // t1 = LN(t + proj): fp32 -> fB, bf16 -> Tb (reused)
    ln_k<<<25088, 256, 0, stream>>>(fT, fA, ln1_g, ln1_b, fB, Tb);
    // fused FFN (MFMA) -> fA
    ffn_mfma_k<<<784, 256, 0, stream>>>(Tb, w1b, ffn_b1, w2b, ffn_b2, fA);
    // t2 = LN(t1 + ff) -> fT
    ln_k<<<25088, 256, 0, stream>>>(fB, fA, ln2_g, ln2_b, fT, nullptr);
    // back to NCHW -> fA
    ne2nchw_k<<<dim3(784, 1, 2), 256, 0, stream>>>(fT, fA);
    // filter-prediction convs (no relu)
    conv3x3_k<4><<<dim3(196, 8, 2), 256, 0, stream>>>(fA, sf_w1, sf_b1, s1out, 64, 32, 0);
    conv3x3_k<3><<<dim3(196, 3, 2), 256, 0, stream>>>(s1out, sf_w2, sf_b2, filt, 32, 9, 0);
    // channel-sum + per-pixel 3x3 dynamic filter
    ssum_k<<<392, 256, 0, stream>>>(x, sbuf);
    kpn_k<<<392, 256, 0, stream>>>(filt, sbuf, fused);
    // decoder
    conv3x3_k<4><<<dim3(196, 16, 2), 256, 0, stream>>>(fused, dec_w1, dec_b1, fB, 1, 64, 1);
    conv3x3_k<1><<<dim3(196, 1, 2), 256, 0, stream>>>(fB, dec_w2, dec_b2, (float*)d_out, 64, 1, 2);
}

// Round 3
// 537.219 us; speedup vs baseline: 2.9391x; 1.6062x over previous
//
#include <hip/hip_runtime.h>
#include <hip/hip_bf16.h>
#include <cstddef>

#define HW   50176
#define NPIX 100352
#define IW   224

typedef unsigned short ushort_t;
typedef __attribute__((ext_vector_type(8))) short bf16x8;
typedef __attribute__((ext_vector_type(8))) unsigned short ushort8;
typedef __attribute__((ext_vector_type(4))) float f32x4;
typedef __attribute__((ext_vector_type(4))) _Float16 f16x4;
typedef __attribute__((ext_vector_type(8))) _Float16 f16x8;

__device__ inline ushort_t f2bf(float f) {
    __hip_bfloat16 h = __float2bfloat16(f);
    return __builtin_bit_cast(ushort_t, h);
}
__device__ inline float bf2f(ushort_t u) {
    return __uint_as_float(((unsigned)u) << 16);
}
__device__ inline bf16x8 ldg8(const ushort_t* p) {
    return *reinterpret_cast<const bf16x8*>(p);
}
__device__ inline void b2f8(const ushort_t* p, float* f) {
    ushort8 v = *reinterpret_cast<const ushort8*>(p);
#pragma unroll
    for (int i = 0; i < 8; i++) f[i] = bf2f(v[i]);
}

// ---------------------------------------------------------------------------
// weight prep kernels
// ---------------------------------------------------------------------------
__global__ __launch_bounds__(256) void f2bf_k(const float* __restrict__ in,
                                              ushort_t* __restrict__ out, int n)
{
    int i = blockIdx.x * 256 + threadIdx.x;
    if (i < n) out[i] = f2bf(in[i]);
}

// conv weight swizzle: out[(co*9 + t)*Cin + ci] = w[(co*Cin + ci)*9 + t], rows padded
__global__ __launch_bounds__(256) void wswz_k(const float* __restrict__ w,
                                              ushort_t* __restrict__ out,
                                              int Cout, int CoutPad, int Cin)
{
    int idx = blockIdx.x * 256 + threadIdx.x;
    int total = CoutPad * 9 * Cin;
    if (idx >= total) return;
    int ci = idx % Cin;
    int t  = (idx / Cin) % 9;
    int co = idx / (Cin * 9);
    out[idx] = (co < Cout) ? f2bf(w[((size_t)co * Cin + ci) * 9 + t]) : (ushort_t)0;
}

// FFN W2 swizzle to f16, phase2 B-frag layout:
// out[((u*2+ntp)*64 + lane)*8 + ntl*4 + jj] = W2[(ntp*2+ntl)*16 + (lane&15)][u*16 + (lane>>4)*4 + jj]
__global__ __launch_bounds__(256) void w2swz_k(const float* __restrict__ w2,
                                               _Float16* __restrict__ out)
{
    int idx = blockIdx.x * 256 + threadIdx.x;  // < 131072
    if (idx >= 131072) return;
    int h    = idx & 7;
    int lane = (idx >> 3) & 63;
    int cp   = idx >> 9;          // u*2 + ntp
    int ntp  = cp & 1;
    int u    = cp >> 1;
    int ntl  = h >> 2, jj = h & 3;
    int e2 = (ntp * 2 + ntl) * 16 + (lane & 15);
    int j  = u * 16 + (lane >> 4) * 4 + jj;
    out[idx] = (_Float16)w2[(size_t)e2 * 2048 + j];
}

// ---------------------------------------------------------------------------
// conv1: 3->64, per-pixel thread, writes NE bf16 [pix][64], relu
// ---------------------------------------------------------------------------
__global__ __launch_bounds__(256) void conv1_ne_k(const float* __restrict__ x,
                                                  const float* __restrict__ w,
                                                  const float* __restrict__ bias,
                                                  ushort_t* __restrict__ out)
{
    int gid = blockIdx.x * 256 + threadIdx.x;  // < NPIX
    int b = gid >= HW;
    int p = gid - b * HW;
    int y = p / IW, xx = p - y * IW;

    float v[27];
#pragma unroll
    for (int ci = 0; ci < 3; ci++) {
        const float* ip = x + ((size_t)(b * 3 + ci)) * HW;
#pragma unroll
        for (int t = 0; t < 9; t++) {
            int dy = t / 3 - 1, dx = t % 3 - 1;
            int yy = y + dy, xc = xx + dx;
            float tv = 0.f;
            if ((unsigned)yy < (unsigned)IW && (unsigned)xc < (unsigned)IW)
                tv = ip[yy * IW + xc];
            v[ci * 9 + t] = tv;
        }
    }
#pragma unroll
    for (int g = 0; g < 8; g++) {
        ushort8 o8;
#pragma unroll
        for (int i = 0; i < 8; i++) {
            int co = g * 8 + i;
            float a = bias[co];
            const float* wp = w + co * 27;
#pragma unroll
            for (int k = 0; k < 27; k++) a = fmaf(v[k], wp[k], a);
            o8[i] = f2bf(fmaxf(a, 0.f));
        }
        *reinterpret_cast<ushort8*>(out + (size_t)gid * 64 + g * 8) = o8;
    }
}

// ---------------------------------------------------------------------------
// NE-layout MFMA conv 3x3: In [NPIX][KS*32] bf16 -> Out [NPIX][NT*16]
// Wsw: [NT*16][9][KS*32] bf16 (pre-swizzled, rows padded).
// 4 waves/block, 32 pixel-rows/wave. Boundary handled by per-lane masks.
// ---------------------------------------------------------------------------
template<int KS, int NT, int NC, int ACT, bool WF32, bool WB16>
__global__ __launch_bounds__(256) void neconv_k(
    const ushort_t* __restrict__ In, const ushort_t* __restrict__ Wsw,
    const float* __restrict__ bias, float* __restrict__ Of,
    ushort_t* __restrict__ Ob)
{
    const int CIN = KS * 32, LDO = NT * 16;
    int tid = threadIdx.x, wave = tid >> 6, lane = tid & 63;
    int lm = lane & 15, quad = lane >> 4;
    int m0 = blockIdx.x * 128 + wave * 32;

    int m[2], py[2], px[2];
#pragma unroll
    for (int mt = 0; mt < 2; mt++) {
        int mm = m0 + mt * 16 + lm;
        m[mt] = mm;
        int p = mm - (mm >= HW ? HW : 0);
        py[mt] = p / IW;
        px[mt] = p - py[mt] * IW;
    }

    f32x4 acc[2][NT] = {};
    bf16x8 zz = {};

#pragma unroll 3
    for (int t = 0; t < 9; t++) {
        int dy = t / 3 - 1, dx = t % 3 - 1;
        bf16x8 af[2][KS];
#pragma unroll
        for (int mt = 0; mt < 2; mt++) {
            bool ok = (unsigned)(py[mt] + dy) < (unsigned)IW &&
                      (unsigned)(px[mt] + dx) < (unsigned)IW;
            const ushort_t* ip = In + (size_t)(m[mt] + dy * IW + dx) * CIN + quad * 8;
#pragma unroll
            for (int ks = 0; ks < KS; ks++)
                af[mt][ks] = ok ? ldg8(ip + ks * 32) : zz;
        }
#pragma unroll
        for (int nt = 0; nt < NT; nt++) {
            const ushort_t* wp = Wsw + ((size_t)(nt * 16 + lm) * 9 + t) * CIN + quad * 8;
#pragma unroll
            for (int ks = 0; ks < KS; ks++) {
                bf16x8 bfv = ldg8(wp + ks * 32);
#pragma unroll
                for (int mt = 0; mt < 2; mt++)
                    acc[mt][nt] = __builtin_amdgcn_mfma_f32_16x16x32_bf16(
                        af[mt][ks], bfv, acc[mt][nt], 0, 0, 0);
            }
        }
    }

#pragma unroll
    for (int nt = 0; nt < NT; nt++) {
        int col = nt * 16 + lm;
        float bv = (col < NC) ? bias[col] : 0.f;
#pragma unroll
        for (int mt = 0; mt < 2; mt++)
#pragma unroll
            for (int r = 0; r < 4; r++) {
                int row = m0 + mt * 16 + quad * 4 + r;
                float v = acc[mt][nt][r] + bv;
                if (ACT) v = fmaxf(v, 0.f);
                if (WF32) Of[(size_t)row * LDO + col] = v;
                if (WB16) Ob[(size_t)row * LDO + col] = f2bf(v);
            }
    }
}

// ---------------------------------------------------------------------------
// MFMA GEMM (qkv / out-proj): C[row,col] = sum_e A[row,e]*W[col,e] + bias
// ---------------------------------------------------------------------------
template<bool OBF16>
__global__ __launch_bounds__(256) void gemmA64_mfma_k(
    const ushort_t* __restrict__ Ab, const ushort_t* __restrict__ Wb,
    const float* __restrict__ bias, void* __restrict__ Cout, int ldc)
{
    int tid = threadIdx.x, wave = tid >> 6, lane = tid & 63;
    int lm = lane & 15, quad = lane >> 4;
    int row0 = blockIdx.x * 64 + wave * 16;
    int col0 = blockIdx.y * 64;

    bf16x8 a[2];
#pragma unroll
    for (int ks = 0; ks < 2; ks++)
        a[ks] = ldg8(Ab + (size_t)(row0 + lm) * 64 + ks * 32 + quad * 8);

    f32x4 acc[4] = {};
#pragma unroll
    for (int nt = 0; nt < 4; nt++)
#pragma unroll
        for (int ks = 0; ks < 2; ks++) {
            bf16x8 b = ldg8(Wb + (size_t)(col0 + nt * 16 + lm) * 64 + ks * 32 + quad * 8);
            acc[nt] = __builtin_amdgcn_mfma_f32_16x16x32_bf16(a[ks], b, acc[nt], 0, 0, 0);
        }

#pragma unroll
    for (int nt = 0; nt < 4; nt++) {
        float bv = bias[col0 + nt * 16 + lm];
#pragma unroll
        for (int r = 0; r < 4; r++) {
            float v = acc[nt][r] + bv;
            size_t o = (size_t)(row0 + quad * 4 + r) * ldc + col0 + nt * 16 + lm;
            if (OBF16) ((ushort_t*)Cout)[o] = f2bf(v);
            else       ((float*)Cout)[o] = v;
        }
    }
}

// ---------------------------------------------------------------------------
// attention: per (n, h). S=2 -> 2x2 scores. bf16 in/out.
// ---------------------------------------------------------------------------
__global__ __launch_bounds__(256) void attn_k(const ushort_t* __restrict__ qkv,
                                              ushort_t* __restrict__ out)
{
    int gid = blockIdx.x * 256 + threadIdx.x;  // < HW*4
    int n = gid >> 2, h = gid & 3;
    const ushort_t* r0 = qkv + (size_t)n * 192 + h * 16;
    const ushort_t* r1 = qkv + ((size_t)HW + n) * 192 + h * 16;

    float q0[16], k0[16], v0[16], q1[16], k1[16], v1[16];
    b2f8(r0,       q0); b2f8(r0 + 8,   q0 + 8);
    b2f8(r0 + 64,  k0); b2f8(r0 + 72,  k0 + 8);
    b2f8(r0 + 128, v0); b2f8(r0 + 136, v0 + 8);
    b2f8(r1,       q1); b2f8(r1 + 8,   q1 + 8);
    b2f8(r1 + 64,  k1); b2f8(r1 + 72,  k1 + 8);
    b2f8(r1 + 128, v1); b2f8(r1 + 136, v1 + 8);

    float s00 = 0, s01 = 0, s10 = 0, s11 = 0;
#pragma unroll
    for (int d = 0; d < 16; d++) {
        s00 += q0[d] * k0[d]; s01 += q0[d] * k1[d];
        s10 += q1[d] * k0[d]; s11 += q1[d] * k1[d];
    }
    s00 *= 0.25f; s01 *= 0.25f; s10 *= 0.25f; s11 *= 0.25f;

    float m0 = fmaxf(s00, s01);
    float e00 = __expf(s00 - m0), e01 = __expf(s01 - m0);
    float i0 = 1.f / (e00 + e01);
    float p00 = e00 * i0, p01 = e01 * i0;

    float m1 = fmaxf(s10, s11);
    float e10 = __expf(s10 - m1), e11 = __expf(s11 - m1);
    float i1 = 1.f / (e10 + e11);
    float p10 = e10 * i1, p11 = e11 * i1;

    ushort_t* o0 = out + (size_t)n * 64 + h * 16;
    ushort_t* o1 = out + ((size_t)HW + n) * 64 + h * 16;
#pragma unroll
    for (int c = 0; c < 2; c++) {
        ushort8 a0v, a1v;
#pragma unroll
        for (int i = 0; i < 8; i++) {
            int d = c * 8 + i;
            a0v[i] = f2bf(p00 * v0[d] + p01 * v1[d]);
            a1v[i] = f2bf(p10 * v0[d] + p11 * v1[d]);
        }
        *reinterpret_cast<ushort8*>(o0 + c * 8) = a0v;
        *reinterpret_cast<ushort8*>(o1 + c * 8) = a1v;
    }
}

// ---------------------------------------------------------------------------
// layernorm over E=64; fp32 and bf16 outputs both optional
// ---------------------------------------------------------------------------
__global__ __launch_bounds__(256) void ln_k(const float* __restrict__ A,
                                            const float* __restrict__ Bv,
                                            const float* __restrict__ g,
                                            const float* __restrict__ be,
                                            float* __restrict__ of,
                                            ushort_t* __restrict__ ob)
{
    int row = blockIdx.x * 4 + (threadIdx.x >> 6);
    int e = threadIdx.x & 63;
    size_t idx = (size_t)row * 64 + e;
    float x = A[idx] + Bv[idx];
    float s = x;
#pragma unroll
    for (int o = 32; o; o >>= 1) s += __shfl_xor(s, o, 64);
    float mu = s * 0.015625f;
    float xc = x - mu;
    float vv = xc * xc;
#pragma unroll
    for (int o = 32; o; o >>= 1) vv += __shfl_xor(vv, o, 64);
    vv *= 0.015625f;
    float r = g[e] * xc * rsqrtf(vv + 1e-5f) + be[e];
    if (of) of[idx] = r;
    if (ob) ob[idx] = f2bf(r);
}

// ---------------------------------------------------------------------------
// Register-only fused FFN. Phase1 computes H^T (A=W1, B=T1) so its C-layout
// IS the 16x16x16 A-frag layout for phase2. Zero LDS, zero barriers.
// W1b: [2048][64] bf16. W2s: pre-swizzled f16 (see w2swz_k). Ping-pong
// prefetch of each 32-j chunk's weights.
// ---------------------------------------------------------------------------
__global__ __launch_bounds__(256) void ffn2_k(
    const ushort_t* __restrict__ T1b, const ushort_t* __restrict__ W1b,
    const float* __restrict__ B1, const _Float16* __restrict__ W2s,
    const float* __restrict__ B2, float* __restrict__ Out)
{
    int tid = threadIdx.x, wave = tid >> 6, lane = tid & 63;
    int lm = lane & 15, quad = lane >> 4;
    int rowbase = blockIdx.x * 128 + wave * 32;

    // T1 B-frags: chunk-invariant
    bf16x8 Bt[2][2];
#pragma unroll
    for (int mt = 0; mt < 2; mt++)
#pragma unroll
        for (int ks = 0; ks < 2; ks++)
            Bt[mt][ks] = ldg8(T1b + (size_t)(rowbase + mt * 16 + lm) * 64 + ks * 32 + quad * 8);

    f32x4 acc[2][4] = {};

    auto loadc = [&](int c, bf16x8 (&w1)[2][2], f16x8 (&w2)[2][2], float4 (&b1v)[2]) {
#pragma unroll
        for (int s = 0; s < 2; s++) {
            int u = c * 2 + s;
#pragma unroll
            for (int ks = 0; ks < 2; ks++)
                w1[s][ks] = ldg8(W1b + (size_t)(u * 16 + lm) * 64 + ks * 32 + quad * 8);
#pragma unroll
            for (int ntp = 0; ntp < 2; ntp++)
                w2[s][ntp] = *reinterpret_cast<const f16x8*>(
                    W2s + ((size_t)(u * 2 + ntp) * 64 + lane) * 8);
            b1v[s] = *reinterpret_cast<const float4*>(B1 + u * 16 + quad * 4);
        }
    };

    auto compute = [&](bf16x8 (&w1)[2][2], f16x8 (&w2)[2][2], float4 (&b1v)[2]) {
#pragma unroll
        for (int s = 0; s < 2; s++) {
            // phase 1: Ht tile = W1 x T1^T  (D: row=j_local, col=m_local)
            f32x4 h[2] = {};
#pragma unroll
            for (int ks = 0; ks < 2; ks++)
#pragma unroll
                for (int mt = 0; mt < 2; mt++)
                    h[mt] = __builtin_amdgcn_mfma_f32_16x16x32_bf16(
                        w1[s][ks], Bt[mt][ks], h[mt], 0, 0, 0);
            float bb[4] = {b1v[s].x, b1v[s].y, b1v[s].z, b1v[s].w};
            f16x4 aH[2];
#pragma unroll
            for (int mt = 0; mt < 2; mt++)
#pragma unroll
                for (int r = 0; r < 4; r++)
                    aH[mt][r] = (_Float16)fmaxf(h[mt][r] + bb[r], 0.f);
            // phase 2: acc += H x W2chunk (16x16x16 f16, A-frag = aH directly)
#pragma unroll
            for (int ntp = 0; ntp < 2; ntp++) {
                f16x4 blo = __builtin_shufflevector(w2[s][ntp], w2[s][ntp], 0, 1, 2, 3);
                f16x4 bhi = __builtin_shufflevector(w2[s][ntp], w2[s][ntp], 4, 5, 6, 7);
#pragma unroll
                for (int mt = 0; mt < 2; mt++) {
                    acc[mt][ntp * 2 + 0] = __builtin_amdgcn_mfma_f32_16x16x16f16(
                        aH[mt], blo, acc[mt][ntp * 2 + 0], 0, 0, 0);
                    acc[mt][ntp * 2 + 1] = __builtin_amdgcn_mfma_f32_16x16x16f16(
                        aH[mt], bhi, acc[mt][ntp * 2 + 1], 0, 0, 0);
                }
            }
        }
    };

    bf16x8 w1a[2][2]; f16x8 w2a[2][2]; float4 b1a[2];
    bf16x8 w1b_[2][2]; f16x8 w2b_[2][2]; float4 b1b_[2];
    loadc(0, w1a, w2a, b1a);
    for (int c = 0; c < 64; c += 2) {
        loadc(c + 1, w1b_, w2b_, b1b_);
        compute(w1a, w2a, b1a);
        loadc(c + 2 < 64 ? c + 2 : 63, w1a, w2a, b1a);
        compute(w1b_, w2b_, b1b_);
    }

#pragma unroll
    for (int nt = 0; nt < 4; nt++) {
        float bo = B2[nt * 16 + lm];
#pragma unroll
        for (int mt = 0; mt < 2; mt++)
#pragma unroll
            for (int r = 0; r < 4; r++)
                Out[(size_t)(rowbase + mt * 16 + quad * 4 + r) * 64 + nt * 16 + lm] =
                    acc[mt][nt][r] + bo;
    }
}

// ---------------------------------------------------------------------------
// conv 3x3 SAME, NCHW fp32 (decoder only)
// ---------------------------------------------------------------------------
template<int COB>
__global__ __launch_bounds__(256) void conv3x3_k(
    const float* __restrict__ in, const float* __restrict__ w,
    const float* __restrict__ bias, float* __restrict__ out,
    int Cin, int Cout, int act)
{
    int pix = blockIdx.x * 256 + threadIdx.x;
    int co0 = blockIdx.y * COB;
    int b   = blockIdx.z;
    int y  = pix / IW;
    int xx = pix - y * IW;

    float acc[COB];
#pragma unroll
    for (int c = 0; c < COB; c++) acc[c] = bias[co0 + c];

    const float* wb = w + (size_t)co0 * Cin * 9;

    for (int ci = 0; ci < Cin; ci++) {
        const float* ip = in + ((size_t)(b * Cin + ci)) * HW;
        float v[9];
#pragma unroll
        for (int ky = 0; ky < 3; ky++) {
            int yy = y + ky - 1;
#pragma unroll
            for (int kx = 0; kx < 3; kx++) {
                int xc = xx + kx - 1;
                float t = 0.f;
                if ((unsigned)yy < (unsigned)IW && (unsigned)xc < (unsigned)IW)
                    t = ip[yy * IW + xc];
                v[ky * 3 + kx] = t;
            }
        }
#pragma unroll
        for (int c = 0; c < COB; c++) {
            const float* wp = wb + (size_t)c * Cin * 9 + ci * 9;
#pragma unroll
            for (int k = 0; k < 9; k++) acc[c] = fmaf(v[k], wp[k], acc[c]);
        }
    }

#pragma unroll
    for (int c = 0; c < COB; c++) {
        float r = acc[c];
        if (act == 1) r = fmaxf(r, 0.f);
        else if (act == 2) r = 1.f / (1.f + __expf(-r));
        out[((size_t)(b * Cout + co0 + c)) * HW + pix] = r;
    }
}

// ---------------------------------------------------------------------------
__global__ __launch_bounds__(256) void ssum_k(const float* __restrict__ x,
                                              float* __restrict__ s)
{
    int gid = blockIdx.x * 256 + threadIdx.x;
    int b = gid / HW;
    int p = gid - b * HW;
    const float* xp = x + (size_t)b * 3 * HW + p;
    s[gid] = xp[0] + xp[HW] + xp[2 * HW];
}

// KPN fuse; filters in NE-padded layout [pix][16] (taps 0..8 valid)
__global__ __launch_bounds__(256) void kpn_k(const float* __restrict__ f,
                                             const float* __restrict__ s,
                                             float* __restrict__ out)
{
    int gid = blockIdx.x * 256 + threadIdx.x;
    int b = gid / HW;
    int p = gid - b * HW;
    int y = p / IW, x = p - y * IW;
    const float* fp = f + (size_t)gid * 16;
    const float* sp = s + (size_t)b * HW;
    float acc = 0.f;
#pragma unroll
    for (int u = 0; u < 3; u++) {
        int yy = y + u - 1;
        if ((unsigned)yy >= (unsigned)IW) continue;
#pragma unroll
        for (int v = 0; v < 3; v++) {
            int xx = x + v - 1;
            if ((unsigned)xx >= (unsigned)IW) continue;
            acc += fp[u * 3 + v] * sp[yy * IW + xx];
        }
    }
    out[gid] = acc;
}

// ---------------------------------------------------------------------------
extern "C" void kernel_launch(void* const* d_in, const int* in_sizes, int n_in,
                              void* d_out, int out_size, void* d_ws, size_t ws_size,
                              hipStream_t stream)
{
    const float* x      = (const float*)d_in[0];
    const float* enc_w1 = (const float*)d_in[1];
    const float* enc_b1 = (const float*)d_in[2];
    const float* enc_w2 = (const float*)d_in[3];
    const float* enc_b2 = (const float*)d_in[4];
    const float* in_w   = (const float*)d_in[5];
    const float* in_b   = (const float*)d_in[6];
    const float* out_w  = (const float*)d_in[7];
    const float* out_b  = (const float*)d_in[8];
    const float* ln1_g  = (const float*)d_in[9];
    const float* ln1_b  = (const float*)d_in[10];
    const float* ffn_w1 = (const float*)d_in[11];
    const float* ffn_b1 = (const float*)d_in[12];
    const float* ffn_w2 = (const float*)d_in[13];
    const float* ffn_b2 = (const float*)d_in[14];
    const float* ln2_g  = (const float*)d_in[15];
    const float* ln2_b  = (const float*)d_in[16];
    const float* sf_w1  = (const float*)d_in[17];
    const float* sf_b1  = (const float*)d_in[18];
    const float* sf_w2  = (const float*)d_in[19];
    const float* sf_b2  = (const float*)d_in[20];
    const float* dec_w1 = (const float*)d_in[21];
    const float* dec_b1 = (const float*)d_in[22];
    const float* dec_w2 = (const float*)d_in[23];
    const float* dec_b2 = (const float*)d_in[24];

    float* ws = (float*)d_ws;
    const size_t SZ = (size_t)NPIX * 64;

    float*    fT   = ws;                                   // conv2 f32 NE
    float*    fA   = ws + SZ;                              // outproj / ffn out
    float*    fB   = ws + 2 * SZ;                          // t1 f32 / dec1 out
    ushort_t* QKVb = (ushort_t*)(ws + 3 * SZ);             // 1.5 SZ
    ushort_t* ATb  = (ushort_t*)(ws + 9 * SZ / 2);         // 0.5 SZ
    ushort_t* E1b  = (ushort_t*)(ws + 5 * SZ);             // conv1 out / T1b
    ushort_t* Tb   = (ushort_t*)(ws + 11 * SZ / 2);        // conv2 bf16 / Tb2
    ushort_t* wu   = (ushort_t*)(ws + 6 * SZ);             // weights
    ushort_t* in_wb  = wu;                                 // 12288
    ushort_t* out_wb = wu + 12288;                         // 4096
    ushort_t* w1b    = wu + 16384;                         // 131072
    _Float16* w2s    = (_Float16*)(wu + 147456);           // 131072 halves
    ushort_t* wc2    = wu + 278528;                        // 36864
    ushort_t* ws1    = wu + 315392;                        // 18432
    ushort_t* ws2    = wu + 333824;                        // 4608
    // late-stage scratch (QKV region dead after attention):
    ushort_t* s1b   = (ushort_t*)(ws + 3 * SZ);            // NPIX*32 bf16
    float*    filtp = ws + 3 * SZ + SZ / 4;                // NPIX*16 f32
    float*    sbuf  = ws + 3 * SZ + SZ / 2;                // NPIX
    float*    fused = sbuf + NPIX;                         // NPIX

    // ---- weight prep ----
    f2bf_k<<<48,  256, 0, stream>>>(in_w,   in_wb,  12288);
    f2bf_k<<<16,  256, 0, stream>>>(out_w,  out_wb, 4096);
    f2bf_k<<<512, 256, 0, stream>>>(ffn_w1, w1b,    131072);
    w2swz_k<<<512, 256, 0, stream>>>(ffn_w2, w2s);
    wswz_k<<<144, 256, 0, stream>>>(enc_w2, wc2, 64, 64, 64);
    wswz_k<<<72,  256, 0, stream>>>(sf_w1,  ws1, 32, 32, 64);
    wswz_k<<<18,  256, 0, stream>>>(sf_w2,  ws2, 9,  16, 32);

    // ---- encoder ----
    conv1_ne_k<<<392, 256, 0, stream>>>(x, enc_w1, enc_b1, E1b);
    neconv_k<2, 4, 64, 1, true, true><<<784, 256, 0, stream>>>(E1b, wc2, enc_b2, fT, Tb);
    // ---- transformer ----
    gemmA64_mfma_k<true><<<dim3(1568, 3), 256, 0, stream>>>(Tb, in_wb, in_b, QKVb, 192);
    attn_k<<<784, 256, 0, stream>>>(QKVb, ATb);
    gemmA64_mfma_k<false><<<dim3(1568, 1), 256, 0, stream>>>(ATb, out_wb, out_b, fA, 64);
    ln_k<<<25088, 256, 0, stream>>>(fT, fA, ln1_g, ln1_b, fB, E1b);   // t1: f32->fB, bf16->E1b
    ffn2_k<<<784, 256, 0, stream>>>(E1b, w1b, ffn_b1, w2s, ffn_b2, fA);
    ln_k<<<25088, 256, 0, stream>>>(fB, fA, ln2_g, ln2_b, nullptr, Tb); // t2 bf16 -> Tb
    // ---- filter prediction (NE MFMA convs) ----
    neconv_k<2, 2, 32, 0, false, true><<<784, 256, 0, stream>>>(Tb, ws1, sf_b1, nullptr, s1b);
    neconv_k<1, 1, 9, 0, true, false><<<784, 256, 0, stream>>>(s1b, ws2, sf_b2, filtp, nullptr);
    // ---- KPN fuse ----
    ssum_k<<<392, 256, 0, stream>>>(x, sbuf);
    kpn_k<<<392, 256, 0, stream>>>(filtp, sbuf, fused);
    // ---- decoder (fp32) ----
    conv3x3_k<4><<<dim3(196, 16, 2), 256, 0, stream>>>(fused, dec_w1, dec_b1, fB, 1, 64, 1);
    conv3x3_k<1><<<dim3(196, 1, 2), 256, 0, stream>>>(fB, dec_w2, dec_b2, (float*)d_out, 64, 1, 2);
}

// Round 4
// 484.215 us; speedup vs baseline: 3.2608x; 1.1095x over previous
//
#include <hip/hip_runtime.h>
#include <hip/hip_bf16.h>
#include <cstddef>

#define HW   50176
#define NPIX 100352
#define IW   224

typedef unsigned short ushort_t;
typedef __attribute__((ext_vector_type(8))) short bf16x8;
typedef __attribute__((ext_vector_type(8))) unsigned short ushort8;
typedef __attribute__((ext_vector_type(4))) float f32x4;
typedef __attribute__((ext_vector_type(4))) _Float16 f16x4;
typedef __attribute__((ext_vector_type(8))) _Float16 f16x8;

__device__ inline ushort_t f2bf(float f) {
    __hip_bfloat16 h = __float2bfloat16(f);
    return __builtin_bit_cast(ushort_t, h);
}
__device__ inline float bf2f(ushort_t u) {
    return __uint_as_float(((unsigned)u) << 16);
}
__device__ inline bf16x8 ldg8(const ushort_t* p) {
    return *reinterpret_cast<const bf16x8*>(p);
}
__device__ inline void b2f8(const ushort_t* p, float* f) {
    ushort8 v = *reinterpret_cast<const ushort8*>(p);
#pragma unroll
    for (int i = 0; i < 8; i++) f[i] = bf2f(v[i]);
}

// ---------------------------------------------------------------------------
// single merged weight-prep kernel (replaces 7 launches)
// ---------------------------------------------------------------------------
__device__ inline void wswz_one(const float* __restrict__ w, ushort_t* __restrict__ out,
                                int idx, int Cout, int Cin)
{
    int ci = idx % Cin;
    int t  = (idx / Cin) % 9;
    int co = idx / (Cin * 9);
    out[idx] = (co < Cout) ? f2bf(w[((size_t)co * Cin + ci) * 9 + t]) : (ushort_t)0;
}

__global__ __launch_bounds__(256) void prep_k(
    const float* __restrict__ in_w,  ushort_t* __restrict__ in_wb,
    const float* __restrict__ out_w, ushort_t* __restrict__ out_wb,
    const float* __restrict__ w1,    ushort_t* __restrict__ w1b,
    const float* __restrict__ w2,    _Float16* __restrict__ w2s,
    const float* __restrict__ ec2,   ushort_t* __restrict__ wc2,
    const float* __restrict__ s1,    ushort_t* __restrict__ ws1,
    const float* __restrict__ s2,    ushort_t* __restrict__ ws2)
{
    int idx = blockIdx.x * 256 + threadIdx.x;
    if (idx < 12288) { in_wb[idx] = f2bf(in_w[idx]); return; }
    idx -= 12288;
    if (idx < 4096)  { out_wb[idx] = f2bf(out_w[idx]); return; }
    idx -= 4096;
    if (idx < 131072){ w1b[idx] = f2bf(w1[idx]); return; }
    idx -= 131072;
    if (idx < 131072){
        // W2 swizzle -> f16 phase2 B-frag layout
        int h    = idx & 7;
        int lane = (idx >> 3) & 63;
        int cp   = idx >> 9;          // u*2 + ntp
        int ntp  = cp & 1;
        int u    = cp >> 1;
        int ntl  = h >> 2, jj = h & 3;
        int e2 = (ntp * 2 + ntl) * 16 + (lane & 15);
        int j  = u * 16 + (lane >> 4) * 4 + jj;
        w2s[idx] = (_Float16)w2[(size_t)e2 * 2048 + j];
        return;
    }
    idx -= 131072;
    if (idx < 36864) { wswz_one(ec2, wc2, idx, 64, 64); return; }
    idx -= 36864;
    if (idx < 18432) { wswz_one(s1, ws1, idx, 32, 64); return; }
    idx -= 18432;
    if (idx < 4608)  { wswz_one(s2, ws2, idx, 9, 32); return; }
}

// ---------------------------------------------------------------------------
// conv1: 3->64, per-pixel thread, writes NE bf16 [pix][64], relu
// ---------------------------------------------------------------------------
__global__ __launch_bounds__(256) void conv1_ne_k(const float* __restrict__ x,
                                                  const float* __restrict__ w,
                                                  const float* __restrict__ bias,
                                                  ushort_t* __restrict__ out)
{
    int gid = blockIdx.x * 256 + threadIdx.x;  // < NPIX
    int b = gid >= HW;
    int p = gid - b * HW;
    int y = p / IW, xx = p - y * IW;

    float v[27];
#pragma unroll
    for (int ci = 0; ci < 3; ci++) {
        const float* ip = x + ((size_t)(b * 3 + ci)) * HW;
#pragma unroll
        for (int t = 0; t < 9; t++) {
            int dy = t / 3 - 1, dx = t % 3 - 1;
            int yy = y + dy, xc = xx + dx;
            float tv = 0.f;
            if ((unsigned)yy < (unsigned)IW && (unsigned)xc < (unsigned)IW)
                tv = ip[yy * IW + xc];
            v[ci * 9 + t] = tv;
        }
    }
#pragma unroll
    for (int g = 0; g < 8; g++) {
        ushort8 o8;
#pragma unroll
        for (int i = 0; i < 8; i++) {
            int co = g * 8 + i;
            float a = bias[co];
            const float* wp = w + co * 27;
#pragma unroll
            for (int k = 0; k < 27; k++) a = fmaf(v[k], wp[k], a);
            o8[i] = f2bf(fmaxf(a, 0.f));
        }
        *reinterpret_cast<ushort8*>(out + (size_t)gid * 64 + g * 8) = o8;
    }
}

// ---------------------------------------------------------------------------
// NE-layout MFMA conv 3x3 (unchanged from R3)
// ---------------------------------------------------------------------------
template<int KS, int NT, int NC, int ACT, bool WF32, bool WB16>
__global__ __launch_bounds__(256) void neconv_k(
    const ushort_t* __restrict__ In, const ushort_t* __restrict__ Wsw,
    const float* __restrict__ bias, float* __restrict__ Of,
    ushort_t* __restrict__ Ob)
{
    const int CIN = KS * 32, LDO = NT * 16;
    int tid = threadIdx.x, wave = tid >> 6, lane = tid & 63;
    int lm = lane & 15, quad = lane >> 4;
    int m0 = blockIdx.x * 128 + wave * 32;

    int m[2], py[2], px[2];
#pragma unroll
    for (int mt = 0; mt < 2; mt++) {
        int mm = m0 + mt * 16 + lm;
        m[mt] = mm;
        int p = mm - (mm >= HW ? HW : 0);
        py[mt] = p / IW;
        px[mt] = p - py[mt] * IW;
    }

    f32x4 acc[2][NT] = {};
    bf16x8 zz = {};

#pragma unroll 3
    for (int t = 0; t < 9; t++) {
        int dy = t / 3 - 1, dx = t % 3 - 1;
        bf16x8 af[2][KS];
#pragma unroll
        for (int mt = 0; mt < 2; mt++) {
            bool ok = (unsigned)(py[mt] + dy) < (unsigned)IW &&
                      (unsigned)(px[mt] + dx) < (unsigned)IW;
            const ushort_t* ip = In + (size_t)(m[mt] + dy * IW + dx) * CIN + quad * 8;
#pragma unroll
            for (int ks = 0; ks < KS; ks++)
                af[mt][ks] = ok ? ldg8(ip + ks * 32) : zz;
        }
#pragma unroll
        for (int nt = 0; nt < NT; nt++) {
            const ushort_t* wp = Wsw + ((size_t)(nt * 16 + lm) * 9 + t) * CIN + quad * 8;
#pragma unroll
            for (int ks = 0; ks < KS; ks++) {
                bf16x8 bfv = ldg8(wp + ks * 32);
#pragma unroll
                for (int mt = 0; mt < 2; mt++)
                    acc[mt][nt] = __builtin_amdgcn_mfma_f32_16x16x32_bf16(
                        af[mt][ks], bfv, acc[mt][nt], 0, 0, 0);
            }
        }
    }

#pragma unroll
    for (int nt = 0; nt < NT; nt++) {
        int col = nt * 16 + lm;
        float bv = (col < NC) ? bias[col] : 0.f;
#pragma unroll
        for (int mt = 0; mt < 2; mt++)
#pragma unroll
            for (int r = 0; r < 4; r++) {
                int row = m0 + mt * 16 + quad * 4 + r;
                float v = acc[mt][nt][r] + bv;
                if (ACT) v = fmaxf(v, 0.f);
                if (WF32) Of[(size_t)row * LDO + col] = v;
                if (WB16) Ob[(size_t)row * LDO + col] = f2bf(v);
            }
    }
}

// ---------------------------------------------------------------------------
// MFMA GEMM (qkv): C[row,col] = sum_e A[row,e]*W[col,e] + bias, bf16 out
// ---------------------------------------------------------------------------
__global__ __launch_bounds__(256) void gemmA64_mfma_k(
    const ushort_t* __restrict__ Ab, const ushort_t* __restrict__ Wb,
    const float* __restrict__ bias, ushort_t* __restrict__ Cout, int ldc)
{
    int tid = threadIdx.x, wave = tid >> 6, lane = tid & 63;
    int lm = lane & 15, quad = lane >> 4;
    int row0 = blockIdx.x * 64 + wave * 16;
    int col0 = blockIdx.y * 64;

    bf16x8 a[2];
#pragma unroll
    for (int ks = 0; ks < 2; ks++)
        a[ks] = ldg8(Ab + (size_t)(row0 + lm) * 64 + ks * 32 + quad * 8);

    f32x4 acc[4] = {};
#pragma unroll
    for (int nt = 0; nt < 4; nt++)
#pragma unroll
        for (int ks = 0; ks < 2; ks++) {
            bf16x8 b = ldg8(Wb + (size_t)(col0 + nt * 16 + lm) * 64 + ks * 32 + quad * 8);
            acc[nt] = __builtin_amdgcn_mfma_f32_16x16x32_bf16(a[ks], b, acc[nt], 0, 0, 0);
        }

#pragma unroll
    for (int nt = 0; nt < 4; nt++) {
        float bv = bias[col0 + nt * 16 + lm];
#pragma unroll
        for (int r = 0; r < 4; r++) {
            float v = acc[nt][r] + bv;
            Cout[(size_t)(row0 + quad * 4 + r) * ldc + col0 + nt * 16 + lm] = f2bf(v);
        }
    }
}

// ---------------------------------------------------------------------------
// out-proj + residual + LN1 fused. Wave = 16 rows x all 64 cols.
// Writes t1 as f32 (ffn residual) and bf16 (ffn input).
// ---------------------------------------------------------------------------
__global__ __launch_bounds__(256) void oproj_ln_k(
    const ushort_t* __restrict__ Ab, const ushort_t* __restrict__ Wb,
    const float* __restrict__ bias, const float* __restrict__ Res,
    const float* __restrict__ g, const float* __restrict__ be,
    float* __restrict__ Of, ushort_t* __restrict__ Ob)
{
    int tid = threadIdx.x, wave = tid >> 6, lane = tid & 63;
    int lm = lane & 15, quad = lane >> 4;
    int row0 = blockIdx.x * 64 + wave * 16;

    bf16x8 a[2];
#pragma unroll
    for (int ks = 0; ks < 2; ks++)
        a[ks] = ldg8(Ab + (size_t)(row0 + lm) * 64 + ks * 32 + quad * 8);

    f32x4 acc[4] = {};
#pragma unroll
    for (int nt = 0; nt < 4; nt++)
#pragma unroll
        for (int ks = 0; ks < 2; ks++) {
            bf16x8 b = ldg8(Wb + (size_t)(nt * 16 + lm) * 64 + ks * 32 + quad * 8);
            acc[nt] = __builtin_amdgcn_mfma_f32_16x16x32_bf16(a[ks], b, acc[nt], 0, 0, 0);
        }

    float bv[4], gv[4], bev[4];
#pragma unroll
    for (int nt = 0; nt < 4; nt++) {
        bv[nt]  = bias[nt * 16 + lm];
        gv[nt]  = g[nt * 16 + lm];
        bev[nt] = be[nt * 16 + lm];
    }

#pragma unroll
    for (int r = 0; r < 4; r++) {
        int row = row0 + quad * 4 + r;
        float v[4]; float s = 0.f;
#pragma unroll
        for (int nt = 0; nt < 4; nt++) {
            v[nt] = acc[nt][r] + bv[nt] + Res[(size_t)row * 64 + nt * 16 + lm];
            s += v[nt];
        }
#pragma unroll
        for (int o = 8; o; o >>= 1) s += __shfl_xor(s, o, 64);
        float mu = s * 0.015625f;
        float q = 0.f;
#pragma unroll
        for (int nt = 0; nt < 4; nt++) { v[nt] -= mu; q += v[nt] * v[nt]; }
#pragma unroll
        for (int o = 8; o; o >>= 1) q += __shfl_xor(q, o, 64);
        float rstd = rsqrtf(q * 0.015625f + 1e-5f);
#pragma unroll
        for (int nt = 0; nt < 4; nt++) {
            float o_ = gv[nt] * v[nt] * rstd + bev[nt];
            size_t off = (size_t)row * 64 + nt * 16 + lm;
            Of[off] = o_;
            Ob[off] = f2bf(o_);
        }
    }
}

// ---------------------------------------------------------------------------
// attention: per (n, h). S=2 -> 2x2 scores. bf16 in/out.
// ---------------------------------------------------------------------------
__global__ __launch_bounds__(256) void attn_k(const ushort_t* __restrict__ qkv,
                                              ushort_t* __restrict__ out)
{
    int gid = blockIdx.x * 256 + threadIdx.x;  // < HW*4
    int n = gid >> 2, h = gid & 3;
    const ushort_t* r0 = qkv + (size_t)n * 192 + h * 16;
    const ushort_t* r1 = qkv + ((size_t)HW + n) * 192 + h * 16;

    float q0[16], k0[16], v0[16], q1[16], k1[16], v1[16];
    b2f8(r0,       q0); b2f8(r0 + 8,   q0 + 8);
    b2f8(r0 + 64,  k0); b2f8(r0 + 72,  k0 + 8);
    b2f8(r0 + 128, v0); b2f8(r0 + 136, v0 + 8);
    b2f8(r1,       q1); b2f8(r1 + 8,   q1 + 8);
    b2f8(r1 + 64,  k1); b2f8(r1 + 72,  k1 + 8);
    b2f8(r1 + 128, v1); b2f8(r1 + 136, v1 + 8);

    float s00 = 0, s01 = 0, s10 = 0, s11 = 0;
#pragma unroll
    for (int d = 0; d < 16; d++) {
        s00 += q0[d] * k0[d]; s01 += q0[d] * k1[d];
        s10 += q1[d] * k0[d]; s11 += q1[d] * k1[d];
    }
    s00 *= 0.25f; s01 *= 0.25f; s10 *= 0.25f; s11 *= 0.25f;

    float m0 = fmaxf(s00, s01);
    float e00 = __expf(s00 - m0), e01 = __expf(s01 - m0);
    float i0 = 1.f / (e00 + e01);
    float p00 = e00 * i0, p01 = e01 * i0;

    float m1 = fmaxf(s10, s11);
    float e10 = __expf(s10 - m1), e11 = __expf(s11 - m1);
    float i1 = 1.f / (e10 + e11);
    float p10 = e10 * i1, p11 = e11 * i1;

    ushort_t* o0 = out + (size_t)n * 64 + h * 16;
    ushort_t* o1 = out + ((size_t)HW + n) * 64 + h * 16;
#pragma unroll
    for (int c = 0; c < 2; c++) {
        ushort8 a0v, a1v;
#pragma unroll
        for (int i = 0; i < 8; i++) {
            int d = c * 8 + i;
            a0v[i] = f2bf(p00 * v0[d] + p01 * v1[d]);
            a1v[i] = f2bf(p10 * v0[d] + p11 * v1[d]);
        }
        *reinterpret_cast<ushort8*>(o0 + c * 8) = a0v;
        *reinterpret_cast<ushort8*>(o1 + c * 8) = a1v;
    }
}

// ---------------------------------------------------------------------------
// FFN v3: register-only, mt=4 (64 rows/wave, 256 rows/block), 4-slot weight
// ring with 3-u lookahead, software-pipelined p1/p2, fused residual + LN2.
// Writes t2 bf16 only.
// ---------------------------------------------------------------------------
__global__ __launch_bounds__(256) void ffn3_k(
    const ushort_t* __restrict__ T1b, const float* __restrict__ T1f,
    const ushort_t* __restrict__ W1b, const float* __restrict__ B1,
    const _Float16* __restrict__ W2s, const float* __restrict__ B2,
    const float* __restrict__ g, const float* __restrict__ be,
    ushort_t* __restrict__ OutTb)
{
    int tid = threadIdx.x, wave = tid >> 6, lane = tid & 63;
    int lm = lane & 15, quad = lane >> 4;
    int rowbase = blockIdx.x * 256 + wave * 64;

    // T1 B-frags: chunk-invariant (64 rows)
    bf16x8 Bt[4][2];
#pragma unroll
    for (int mt = 0; mt < 4; mt++)
#pragma unroll
        for (int ks = 0; ks < 2; ks++)
            Bt[mt][ks] = ldg8(T1b + (size_t)(rowbase + mt * 16 + lm) * 64 + ks * 32 + quad * 8);

    f32x4 acc[4][4] = {};

    bf16x8 W1r[4][2];
    f16x8  W2r[4][2];
    float4 B1r[4];

    auto loadW = [&](int u, int s) {
#pragma unroll
        for (int ks = 0; ks < 2; ks++)
            W1r[s][ks] = ldg8(W1b + (size_t)(u * 16 + lm) * 64 + ks * 32 + quad * 8);
#pragma unroll
        for (int ntp = 0; ntp < 2; ntp++)
            W2r[s][ntp] = *reinterpret_cast<const f16x8*>(
                W2s + ((size_t)(u * 2 + ntp) * 64 + lane) * 8);
        B1r[s] = *reinterpret_cast<const float4*>(B1 + u * 16 + quad * 4);
    };

    auto p1 = [&](int s, f32x4 (&h)[4]) {
#pragma unroll
        for (int ks = 0; ks < 2; ks++)
#pragma unroll
            for (int mt = 0; mt < 4; mt++)
                h[mt] = __builtin_amdgcn_mfma_f32_16x16x32_bf16(
                    W1r[s][ks], Bt[mt][ks], h[mt], 0, 0, 0);
    };

    auto cvt = [&](f32x4 (&h)[4], int s, f16x4 (&aH)[4]) {
        float bb[4] = {B1r[s].x, B1r[s].y, B1r[s].z, B1r[s].w};
#pragma unroll
        for (int mt = 0; mt < 4; mt++)
#pragma unroll
            for (int r = 0; r < 4; r++)
                aH[mt][r] = (_Float16)fmaxf(h[mt][r] + bb[r], 0.f);
    };

    auto p2 = [&](int s, f16x4 (&aH)[4]) {
#pragma unroll
        for (int ntp = 0; ntp < 2; ntp++) {
            f16x4 blo = __builtin_shufflevector(W2r[s][ntp], W2r[s][ntp], 0, 1, 2, 3);
            f16x4 bhi = __builtin_shufflevector(W2r[s][ntp], W2r[s][ntp], 4, 5, 6, 7);
#pragma unroll
            for (int mt = 0; mt < 4; mt++) {
                acc[mt][ntp * 2 + 0] = __builtin_amdgcn_mfma_f32_16x16x16f16(
                    aH[mt], blo, acc[mt][ntp * 2 + 0], 0, 0, 0);
                acc[mt][ntp * 2 + 1] = __builtin_amdgcn_mfma_f32_16x16x16f16(
                    aH[mt], bhi, acc[mt][ntp * 2 + 1], 0, 0, 0);
            }
        }
    };

    f16x4 aH[4];
    loadW(0, 0); loadW(1, 1); loadW(2, 2);
    {
        f32x4 h0[4] = {};
        p1(0, h0);
        cvt(h0, 0, aH);
    }
    for (int ub = 0; ub < 128; ub += 4) {
#pragma unroll
        for (int k = 0; k < 4; k++) {
            int u = ub + k;
            int lu = u + 3; if (lu > 127) lu = 127;
            loadW(lu, (k + 3) & 3);          // 3 chunks ahead
            f32x4 hn[4] = {};
            p1((k + 1) & 3, hn);             // phase1 for u+1
            p2(k & 3, aH);                   // phase2 for u (uses aH from prev stage)
            cvt(hn, (k + 1) & 3, aH);        // aH for u+1
        }
    }

    // ---- epilogue: + b2 + residual(t1 f32) -> LN2 -> bf16 ----
    float b2v[4], gv[4], bev[4];
#pragma unroll
    for (int nt = 0; nt < 4; nt++) {
        b2v[nt] = B2[nt * 16 + lm];
        gv[nt]  = g[nt * 16 + lm];
        bev[nt] = be[nt * 16 + lm];
    }
#pragma unroll
    for (int mt = 0; mt < 4; mt++)
#pragma unroll
        for (int r = 0; r < 4; r++) {
            int row = rowbase + mt * 16 + quad * 4 + r;
            float v[4]; float s = 0.f;
#pragma unroll
            for (int nt = 0; nt < 4; nt++) {
                v[nt] = acc[mt][nt][r] + b2v[nt] + T1f[(size_t)row * 64 + nt * 16 + lm];
                s += v[nt];
            }
#pragma unroll
            for (int o = 8; o; o >>= 1) s += __shfl_xor(s, o, 64);
            float mu = s * 0.015625f;
            float q = 0.f;
#pragma unroll
            for (int nt = 0; nt < 4; nt++) { v[nt] -= mu; q += v[nt] * v[nt]; }
#pragma unroll
            for (int o = 8; o; o >>= 1) q += __shfl_xor(q, o, 64);
            float rstd = rsqrtf(q * 0.015625f + 1e-5f);
#pragma unroll
            for (int nt = 0; nt < 4; nt++)
                OutTb[(size_t)row * 64 + nt * 16 + lm] =
                    f2bf(gv[nt] * v[nt] * rstd + bev[nt]);
        }
}

// ---------------------------------------------------------------------------
// conv 3x3 SAME, NCHW fp32 (decoder only)
// ---------------------------------------------------------------------------
template<int COB>
__global__ __launch_bounds__(256) void conv3x3_k(
    const float* __restrict__ in, const float* __restrict__ w,
    const float* __restrict__ bias, float* __restrict__ out,
    int Cin, int Cout, int act)
{
    int pix = blockIdx.x * 256 + threadIdx.x;
    int co0 = blockIdx.y * COB;
    int b   = blockIdx.z;
    int y  = pix / IW;
    int xx = pix - y * IW;

    float acc[COB];
#pragma unroll
    for (int c = 0; c < COB; c++) acc[c] = bias[co0 + c];

    const float* wb = w + (size_t)co0 * Cin * 9;

    for (int ci = 0; ci < Cin; ci++) {
        const float* ip = in + ((size_t)(b * Cin + ci)) * HW;
        float v[9];
#pragma unroll
        for (int ky = 0; ky < 3; ky++) {
            int yy = y + ky - 1;
#pragma unroll
            for (int kx = 0; kx < 3; kx++) {
                int xc = xx + kx - 1;
                float t = 0.f;
                if ((unsigned)yy < (unsigned)IW && (unsigned)xc < (unsigned)IW)
                    t = ip[yy * IW + xc];
                v[ky * 3 + kx] = t;
            }
        }
#pragma unroll
        for (int c = 0; c < COB; c++) {
            const float* wp = wb + (size_t)c * Cin * 9 + ci * 9;
#pragma unroll
            for (int k = 0; k < 9; k++) acc[c] = fmaf(v[k], wp[k], acc[c]);
        }
    }

#pragma unroll
    for (int c = 0; c < COB; c++) {
        float r = acc[c];
        if (act == 1) r = fmaxf(r, 0.f);
        else if (act == 2) r = 1.f / (1.f + __expf(-r));
        out[((size_t)(b * Cout + co0 + c)) * HW + pix] = r;
    }
}

// ---------------------------------------------------------------------------
__global__ __launch_bounds__(256) void ssum_k(const float* __restrict__ x,
                                              float* __restrict__ s)
{
    int gid = blockIdx.x * 256 + threadIdx.x;
    int b = gid / HW;
    int p = gid - b * HW;
    const float* xp = x + (size_t)b * 3 * HW + p;
    s[gid] = xp[0] + xp[HW] + xp[2 * HW];
}

// KPN fuse; filters in NE-padded layout [pix][16] (taps 0..8 valid)
__global__ __launch_bounds__(256) void kpn_k(const float* __restrict__ f,
                                             const float* __restrict__ s,
                                             float* __restrict__ out)
{
    int gid = blockIdx.x * 256 + threadIdx.x;
    int b = gid / HW;
    int p = gid - b * HW;
    int y = p / IW, x = p - y * IW;
    const float* fp = f + (size_t)gid * 16;
    const float* sp = s + (size_t)b * HW;
    float acc = 0.f;
#pragma unroll
    for (int u = 0; u < 3; u++) {
        int yy = y + u - 1;
        if ((unsigned)yy >= (unsigned)IW) continue;
#pragma unroll
        for (int v = 0; v < 3; v++) {
            int xx = x + v - 1;
            if ((unsigned)xx >= (unsigned)IW) continue;
            acc += fp[u * 3 + v] * sp[yy * IW + xx];
        }
    }
    out[gid] = acc;
}

// ---------------------------------------------------------------------------
extern "C" void kernel_launch(void* const* d_in, const int* in_sizes, int n_in,
                              void* d_out, int out_size, void* d_ws, size_t ws_size,
                              hipStream_t stream)
{
    const float* x      = (const float*)d_in[0];
    const float* enc_w1 = (const float*)d_in[1];
    const float* enc_b1 = (const float*)d_in[2];
    const float* enc_w2 = (const float*)d_in[3];
    const float* enc_b2 = (const float*)d_in[4];
    const float* in_w   = (const float*)d_in[5];
    const float* in_b   = (const float*)d_in[6];
    const float* out_w  = (const float*)d_in[7];
    const float* out_b  = (const float*)d_in[8];
    const float* ln1_g  = (const float*)d_in[9];
    const float* ln1_b  = (const float*)d_in[10];
    const float* ffn_w1 = (const float*)d_in[11];
    const float* ffn_b1 = (const float*)d_in[12];
    const float* ffn_w2 = (const float*)d_in[13];
    const float* ffn_b2 = (const float*)d_in[14];
    const float* ln2_g  = (const float*)d_in[15];
    const float* ln2_b  = (const float*)d_in[16];
    const float* sf_w1  = (const float*)d_in[17];
    const float* sf_b1  = (const float*)d_in[18];
    const float* sf_w2  = (const float*)d_in[19];
    const float* sf_b2  = (const float*)d_in[20];
    const float* dec_w1 = (const float*)d_in[21];
    const float* dec_b1 = (const float*)d_in[22];
    const float* dec_w2 = (const float*)d_in[23];
    const float* dec_b2 = (const float*)d_in[24];

    float* ws = (float*)d_ws;
    const size_t SZ = (size_t)NPIX * 64;

    float*    fT   = ws;                                   // conv2 f32 NE
    float*    fB   = ws + 2 * SZ;                          // t1 f32 / dec1 out
    ushort_t* QKVb = (ushort_t*)(ws + 3 * SZ);             // 1.5 SZ
    ushort_t* ATb  = (ushort_t*)(ws + 9 * SZ / 2);         // 0.5 SZ
    ushort_t* E1b  = (ushort_t*)(ws + 5 * SZ);             // conv1 out / t1 bf16
    ushort_t* Tb   = (ushort_t*)(ws + 11 * SZ / 2);        // conv2 bf16 / t2 bf16
    ushort_t* wu   = (ushort_t*)(ws + 6 * SZ);             // weights
    ushort_t* in_wb  = wu;                                 // 12288
    ushort_t* out_wb = wu + 12288;                         // 4096
    ushort_t* w1b    = wu + 16384;                         // 131072
    _Float16* w2s    = (_Float16*)(wu + 147456);           // 131072 halves
    ushort_t* wc2    = wu + 278528;                        // 36864
    ushort_t* ws1    = wu + 315392;                        // 18432
    ushort_t* ws2    = wu + 333824;                        // 4608
    // late-stage scratch (QKV region dead after attention):
    ushort_t* s1b   = (ushort_t*)(ws + 3 * SZ);            // NPIX*32 bf16
    float*    filtp = ws + 3 * SZ + SZ / 4;                // NPIX*16 f32
    float*    sbuf  = ws + 3 * SZ + SZ / 2;                // NPIX
    float*    fused = sbuf + NPIX;                         // NPIX

    // ---- merged weight prep (1 launch) ----
    prep_k<<<1322, 256, 0, stream>>>(in_w, in_wb, out_w, out_wb, ffn_w1, w1b,
                                     ffn_w2, w2s, enc_w2, wc2, sf_w1, ws1, sf_w2, ws2);

    // ---- encoder ----
    conv1_ne_k<<<392, 256, 0, stream>>>(x, enc_w1, enc_b1, E1b);
    neconv_k<2, 4, 64, 1, true, true><<<784, 256, 0, stream>>>(E1b, wc2, enc_b2, fT, Tb);
    // ---- transformer ----
    gemmA64_mfma_k<<<dim3(1568, 3), 256, 0, stream>>>(Tb, in_wb, in_b, QKVb, 192);
    attn_k<<<784, 256, 0, stream>>>(QKVb, ATb);
    oproj_ln_k<<<1568, 256, 0, stream>>>(ATb, out_wb, out_b, fT, ln1_g, ln1_b, fB, E1b);
    ffn3_k<<<392, 256, 0, stream>>>(E1b, fB, w1b, ffn_b1, w2s, ffn_b2, ln2_g, ln2_b, Tb);
    // ---- filter prediction (NE MFMA convs) ----
    neconv_k<2, 2, 32, 0, false, true><<<784, 256, 0, stream>>>(Tb, ws1, sf_b1, nullptr, s1b);
    neconv_k<1, 1, 9, 0, true, false><<<784, 256, 0, stream>>>(s1b, ws2, sf_b2, filtp, nullptr);
    // ---- KPN fuse ----
    ssum_k<<<392, 256, 0, stream>>>(x, sbuf);
    kpn_k<<<392, 256, 0, stream>>>(filtp, sbuf, fused);
    // ---- decoder (fp32) ----
    conv3x3_k<4><<<dim3(196, 16, 2), 256, 0, stream>>>(fused, dec_w1, dec_b1, fB, 1, 64, 1);
    conv3x3_k<1><<<dim3(196, 1, 2), 256, 0, stream>>>(fB, dec_w2, dec_b2, (float*)d_out, 64, 1, 2);
}

// Round 5
// 480.076 us; speedup vs baseline: 3.2889x; 1.0086x over previous
//
#include <hip/hip_runtime.h>
#include <hip/hip_bf16.h>
#include <cstddef>

#define HW   50176
#define NPIX 100352
#define IW   224

typedef unsigned short ushort_t;
typedef __attribute__((ext_vector_type(8))) short bf16x8;
typedef __attribute__((ext_vector_type(8))) unsigned short ushort8;
typedef __attribute__((ext_vector_type(4))) float f32x4;
typedef __attribute__((ext_vector_type(4))) _Float16 f16x4;
typedef __attribute__((ext_vector_type(8))) _Float16 f16x8;

__device__ inline ushort_t f2bf(float f) {
    __hip_bfloat16 h = __float2bfloat16(f);
    return __builtin_bit_cast(ushort_t, h);
}
__device__ inline float bf2f(ushort_t u) {
    return __uint_as_float(((unsigned)u) << 16);
}
__device__ inline bf16x8 ldg8(const ushort_t* p) {
    return *reinterpret_cast<const bf16x8*>(p);
}
__device__ inline void b2f8(const ushort_t* p, float* f) {
    ushort8 v = *reinterpret_cast<const ushort8*>(p);
#pragma unroll
    for (int i = 0; i < 8; i++) f[i] = bf2f(v[i]);
}

// ---------------------------------------------------------------------------
// single merged weight-prep kernel
// ---------------------------------------------------------------------------
__device__ inline void wswz_one(const float* __restrict__ w, ushort_t* __restrict__ out,
                                int idx, int Cout, int Cin)
{
    int ci = idx % Cin;
    int t  = (idx / Cin) % 9;
    int co = idx / (Cin * 9);
    out[idx] = (co < Cout) ? f2bf(w[((size_t)co * Cin + ci) * 9 + t]) : (ushort_t)0;
}

__global__ __launch_bounds__(256) void prep_k(
    const float* __restrict__ in_w,  ushort_t* __restrict__ in_wb,
    const float* __restrict__ out_w, ushort_t* __restrict__ out_wb,
    const float* __restrict__ w1,    ushort_t* __restrict__ w1b,
    const float* __restrict__ w2,    _Float16* __restrict__ w2s,
    const float* __restrict__ ec2,   ushort_t* __restrict__ wc2,
    const float* __restrict__ s1,    ushort_t* __restrict__ ws1,
    const float* __restrict__ s2,    ushort_t* __restrict__ ws2)
{
    int idx = blockIdx.x * 256 + threadIdx.x;
    if (idx < 12288) { in_wb[idx] = f2bf(in_w[idx]); return; }
    idx -= 12288;
    if (idx < 4096)  { out_wb[idx] = f2bf(out_w[idx]); return; }
    idx -= 4096;
    if (idx < 131072){ w1b[idx] = f2bf(w1[idx]); return; }
    idx -= 131072;
    if (idx < 131072){
        int h    = idx & 7;
        int lane = (idx >> 3) & 63;
        int cp   = idx >> 9;          // u*2 + ntp
        int ntp  = cp & 1;
        int u    = cp >> 1;
        int ntl  = h >> 2, jj = h & 3;
        int e2 = (ntp * 2 + ntl) * 16 + (lane & 15);
        int j  = u * 16 + (lane >> 4) * 4 + jj;
        w2s[idx] = (_Float16)w2[(size_t)e2 * 2048 + j];
        return;
    }
    idx -= 131072;
    if (idx < 36864) { wswz_one(ec2, wc2, idx, 64, 64); return; }
    idx -= 36864;
    if (idx < 18432) { wswz_one(s1, ws1, idx, 32, 64); return; }
    idx -= 18432;
    if (idx < 4608)  { wswz_one(s2, ws2, idx, 9, 32); return; }
}

// ---------------------------------------------------------------------------
// conv1: 3->64, per-pixel thread, writes NE bf16 [pix][64], relu
// ---------------------------------------------------------------------------
__global__ __launch_bounds__(256) void conv1_ne_k(const float* __restrict__ x,
                                                  const float* __restrict__ w,
                                                  const float* __restrict__ bias,
                                                  ushort_t* __restrict__ out)
{
    int gid = blockIdx.x * 256 + threadIdx.x;  // < NPIX
    int b = gid >= HW;
    int p = gid - b * HW;
    int y = p / IW, xx = p - y * IW;

    float v[27];
#pragma unroll
    for (int ci = 0; ci < 3; ci++) {
        const float* ip = x + ((size_t)(b * 3 + ci)) * HW;
#pragma unroll
        for (int t = 0; t < 9; t++) {
            int dy = t / 3 - 1, dx = t % 3 - 1;
            int yy = y + dy, xc = xx + dx;
            float tv = 0.f;
            if ((unsigned)yy < (unsigned)IW && (unsigned)xc < (unsigned)IW)
                tv = ip[yy * IW + xc];
            v[ci * 9 + t] = tv;
        }
    }
#pragma unroll
    for (int g = 0; g < 8; g++) {
        ushort8 o8;
#pragma unroll
        for (int i = 0; i < 8; i++) {
            int co = g * 8 + i;
            float a = bias[co];
            const float* wp = w + co * 27;
#pragma unroll
            for (int k = 0; k < 27; k++) a = fmaf(v[k], wp[k], a);
            o8[i] = f2bf(fmaxf(a, 0.f));
        }
        *reinterpret_cast<ushort8*>(out + (size_t)gid * 64 + g * 8) = o8;
    }
}

// ---------------------------------------------------------------------------
// NE-layout MFMA conv 3x3
// ---------------------------------------------------------------------------
template<int KS, int NT, int NC, int ACT, bool WF32, bool WB16>
__global__ __launch_bounds__(256) void neconv_k(
    const ushort_t* __restrict__ In, const ushort_t* __restrict__ Wsw,
    const float* __restrict__ bias, float* __restrict__ Of,
    ushort_t* __restrict__ Ob)
{
    const int CIN = KS * 32, LDO = NT * 16;
    int tid = threadIdx.x, wave = tid >> 6, lane = tid & 63;
    int lm = lane & 15, quad = lane >> 4;
    int m0 = blockIdx.x * 128 + wave * 32;

    int m[2], py[2], px[2];
#pragma unroll
    for (int mt = 0; mt < 2; mt++) {
        int mm = m0 + mt * 16 + lm;
        m[mt] = mm;
        int p = mm - (mm >= HW ? HW : 0);
        py[mt] = p / IW;
        px[mt] = p - py[mt] * IW;
    }

    f32x4 acc[2][NT] = {};
    bf16x8 zz = {};

#pragma unroll 3
    for (int t = 0; t < 9; t++) {
        int dy = t / 3 - 1, dx = t % 3 - 1;
        bf16x8 af[2][KS];
#pragma unroll
        for (int mt = 0; mt < 2; mt++) {
            bool ok = (unsigned)(py[mt] + dy) < (unsigned)IW &&
                      (unsigned)(px[mt] + dx) < (unsigned)IW;
            const ushort_t* ip = In + (size_t)(m[mt] + dy * IW + dx) * CIN + quad * 8;
#pragma unroll
            for (int ks = 0; ks < KS; ks++)
                af[mt][ks] = ok ? ldg8(ip + ks * 32) : zz;
        }
#pragma unroll
        for (int nt = 0; nt < NT; nt++) {
            const ushort_t* wp = Wsw + ((size_t)(nt * 16 + lm) * 9 + t) * CIN + quad * 8;
#pragma unroll
            for (int ks = 0; ks < KS; ks++) {
                bf16x8 bfv = ldg8(wp + ks * 32);
#pragma unroll
                for (int mt = 0; mt < 2; mt++)
                    acc[mt][nt] = __builtin_amdgcn_mfma_f32_16x16x32_bf16(
                        af[mt][ks], bfv, acc[mt][nt], 0, 0, 0);
            }
        }
    }

#pragma unroll
    for (int nt = 0; nt < NT; nt++) {
        int col = nt * 16 + lm;
        float bv = (col < NC) ? bias[col] : 0.f;
#pragma unroll
        for (int mt = 0; mt < 2; mt++)
#pragma unroll
            for (int r = 0; r < 4; r++) {
                int row = m0 + mt * 16 + quad * 4 + r;
                float v = acc[mt][nt][r] + bv;
                if (ACT) v = fmaxf(v, 0.f);
                if (WF32) Of[(size_t)row * LDO + col] = v;
                if (WB16) Ob[(size_t)row * LDO + col] = f2bf(v);
            }
    }
}

// ---------------------------------------------------------------------------
// qkv GEMM, one pass over all 192 cols (A read once). bf16 out.
// ---------------------------------------------------------------------------
__global__ __launch_bounds__(256) void gemmQKV_k(
    const ushort_t* __restrict__ Ab, const ushort_t* __restrict__ Wb,
    const float* __restrict__ bias, ushort_t* __restrict__ Cout)
{
    int tid = threadIdx.x, wave = tid >> 6, lane = tid & 63;
    int lm = lane & 15, quad = lane >> 4;
    int row0 = blockIdx.x * 64 + wave * 16;

    bf16x8 a[2];
#pragma unroll
    for (int ks = 0; ks < 2; ks++)
        a[ks] = ldg8(Ab + (size_t)(row0 + lm) * 64 + ks * 32 + quad * 8);

    f32x4 acc[12] = {};
#pragma unroll
    for (int nt = 0; nt < 12; nt++)
#pragma unroll
        for (int ks = 0; ks < 2; ks++) {
            bf16x8 b = ldg8(Wb + (size_t)(nt * 16 + lm) * 64 + ks * 32 + quad * 8);
            acc[nt] = __builtin_amdgcn_mfma_f32_16x16x32_bf16(a[ks], b, acc[nt], 0, 0, 0);
        }

#pragma unroll
    for (int nt = 0; nt < 12; nt++) {
        float bv = bias[nt * 16 + lm];
#pragma unroll
        for (int r = 0; r < 4; r++) {
            float v = acc[nt][r] + bv;
            Cout[(size_t)(row0 + quad * 4 + r) * 192 + nt * 16 + lm] = f2bf(v);
        }
    }
}

// ---------------------------------------------------------------------------
// out-proj + residual(bf16 Tb) + LN1 fused. Writes t1 bf16 only.
// ---------------------------------------------------------------------------
__global__ __launch_bounds__(256) void oproj_ln_k(
    const ushort_t* __restrict__ Ab, const ushort_t* __restrict__ Wb,
    const float* __restrict__ bias, const ushort_t* __restrict__ Res,
    const float* __restrict__ g, const float* __restrict__ be,
    ushort_t* __restrict__ Ob)
{
    int tid = threadIdx.x, wave = tid >> 6, lane = tid & 63;
    int lm = lane & 15, quad = lane >> 4;
    int row0 = blockIdx.x * 64 + wave * 16;

    bf16x8 a[2];
#pragma unroll
    for (int ks = 0; ks < 2; ks++)
        a[ks] = ldg8(Ab + (size_t)(row0 + lm) * 64 + ks * 32 + quad * 8);

    f32x4 acc[4] = {};
#pragma unroll
    for (int nt = 0; nt < 4; nt++)
#pragma unroll
        for (int ks = 0; ks < 2; ks++) {
            bf16x8 b = ldg8(Wb + (size_t)(nt * 16 + lm) * 64 + ks * 32 + quad * 8);
            acc[nt] = __builtin_amdgcn_mfma_f32_16x16x32_bf16(a[ks], b, acc[nt], 0, 0, 0);
        }

    float bv[4], gv[4], bev[4];
#pragma unroll
    for (int nt = 0; nt < 4; nt++) {
        bv[nt]  = bias[nt * 16 + lm];
        gv[nt]  = g[nt * 16 + lm];
        bev[nt] = be[nt * 16 + lm];
    }

#pragma unroll
    for (int r = 0; r < 4; r++) {
        int row = row0 + quad * 4 + r;
        float v[4]; float s = 0.f;
#pragma unroll
        for (int nt = 0; nt < 4; nt++) {
            v[nt] = acc[nt][r] + bv[nt] + bf2f(Res[(size_t)row * 64 + nt * 16 + lm]);
            s += v[nt];
        }
#pragma unroll
        for (int o = 8; o; o >>= 1) s += __shfl_xor(s, o, 64);
        float mu = s * 0.015625f;
        float q = 0.f;
#pragma unroll
        for (int nt = 0; nt < 4; nt++) { v[nt] -= mu; q += v[nt] * v[nt]; }
#pragma unroll
        for (int o = 8; o; o >>= 1) q += __shfl_xor(q, o, 64);
        float rstd = rsqrtf(q * 0.015625f + 1e-5f);
#pragma unroll
        for (int nt = 0; nt < 4; nt++)
            Ob[(size_t)row * 64 + nt * 16 + lm] = f2bf(gv[nt] * v[nt] * rstd + bev[nt]);
    }
}

// ---------------------------------------------------------------------------
// attention: per (n, h). S=2 -> 2x2 scores. bf16 in/out.
// ---------------------------------------------------------------------------
__global__ __launch_bounds__(256) void attn_k(const ushort_t* __restrict__ qkv,
                                              ushort_t* __restrict__ out)
{
    int gid = blockIdx.x * 256 + threadIdx.x;  // < HW*4
    int n = gid >> 2, h = gid & 3;
    const ushort_t* r0 = qkv + (size_t)n * 192 + h * 16;
    const ushort_t* r1 = qkv + ((size_t)HW + n) * 192 + h * 16;

    float q0[16], k0[16], v0[16], q1[16], k1[16], v1[16];
    b2f8(r0,       q0); b2f8(r0 + 8,   q0 + 8);
    b2f8(r0 + 64,  k0); b2f8(r0 + 72,  k0 + 8);
    b2f8(r0 + 128, v0); b2f8(r0 + 136, v0 + 8);
    b2f8(r1,       q1); b2f8(r1 + 8,   q1 + 8);
    b2f8(r1 + 64,  k1); b2f8(r1 + 72,  k1 + 8);
    b2f8(r1 + 128, v1); b2f8(r1 + 136, v1 + 8);

    float s00 = 0, s01 = 0, s10 = 0, s11 = 0;
#pragma unroll
    for (int d = 0; d < 16; d++) {
        s00 += q0[d] * k0[d]; s01 += q0[d] * k1[d];
        s10 += q1[d] * k0[d]; s11 += q1[d] * k1[d];
    }
    s00 *= 0.25f; s01 *= 0.25f; s10 *= 0.25f; s11 *= 0.25f;

    float m0 = fmaxf(s00, s01);
    float e00 = __expf(s00 - m0), e01 = __expf(s01 - m0);
    float i0 = 1.f / (e00 + e01);
    float p00 = e00 * i0, p01 = e01 * i0;

    float m1 = fmaxf(s10, s11);
    float e10 = __expf(s10 - m1), e11 = __expf(s11 - m1);
    float i1 = 1.f / (e10 + e11);
    float p10 = e10 * i1, p11 = e11 * i1;

    ushort_t* o0 = out + (size_t)n * 64 + h * 16;
    ushort_t* o1 = out + ((size_t)HW + n) * 64 + h * 16;
#pragma unroll
    for (int c = 0; c < 2; c++) {
        ushort8 a0v, a1v;
#pragma unroll
        for (int i = 0; i < 8; i++) {
            int d = c * 8 + i;
            a0v[i] = f2bf(p00 * v0[d] + p01 * v1[d]);
            a1v[i] = f2bf(p10 * v0[d] + p11 * v1[d]);
        }
        *reinterpret_cast<ushort8*>(o0 + c * 8) = a0v;
        *reinterpret_cast<ushort8*>(o1 + c * 8) = a1v;
    }
}

// ---------------------------------------------------------------------------
// FFN v4: register-only, mt=2 (32 rows/wave, 128/block, 784 blocks), 4-slot
// weight ring with 3-u lookahead, fused bf16 residual + LN2. Writes t2 bf16.
// ---------------------------------------------------------------------------
__global__ __launch_bounds__(256) void ffn4_k(
    const ushort_t* __restrict__ T1b,
    const ushort_t* __restrict__ W1b, const float* __restrict__ B1,
    const _Float16* __restrict__ W2s, const float* __restrict__ B2,
    const float* __restrict__ g, const float* __restrict__ be,
    ushort_t* __restrict__ OutTb)
{
    int tid = threadIdx.x, wave = tid >> 6, lane = tid & 63;
    int lm = lane & 15, quad = lane >> 4;
    int rowbase = blockIdx.x * 128 + wave * 32;

    bf16x8 Bt[2][2];
#pragma unroll
    for (int mt = 0; mt < 2; mt++)
#pragma unroll
        for (int ks = 0; ks < 2; ks++)
            Bt[mt][ks] = ldg8(T1b + (size_t)(rowbase + mt * 16 + lm) * 64 + ks * 32 + quad * 8);

    f32x4 acc[2][4] = {};

    bf16x8 W1r[4][2];
    f16x8  W2r[4][2];
    float4 B1r[4];

    auto loadW = [&](int u, int s) {
#pragma unroll
        for (int ks = 0; ks < 2; ks++)
            W1r[s][ks] = ldg8(W1b + (size_t)(u * 16 + lm) * 64 + ks * 32 + quad * 8);
#pragma unroll
        for (int ntp = 0; ntp < 2; ntp++)
            W2r[s][ntp] = *reinterpret_cast<const f16x8*>(
                W2s + ((size_t)(u * 2 + ntp) * 64 + lane) * 8);
        B1r[s] = *reinterpret_cast<const float4*>(B1 + u * 16 + quad * 4);
    };

    auto p1 = [&](int s, f32x4 (&h)[2]) {
#pragma unroll
        for (int ks = 0; ks < 2; ks++)
#pragma unroll
            for (int mt = 0; mt < 2; mt++)
                h[mt] = __builtin_amdgcn_mfma_f32_16x16x32_bf16(
                    W1r[s][ks], Bt[mt][ks], h[mt], 0, 0, 0);
    };

    auto cvt = [&](f32x4 (&h)[2], int s, f16x4 (&aH)[2]) {
        float bb[4] = {B1r[s].x, B1r[s].y, B1r[s].z, B1r[s].w};
#pragma unroll
        for (int mt = 0; mt < 2; mt++)
#pragma unroll
            for (int r = 0; r < 4; r++)
                aH[mt][r] = (_Float16)fmaxf(h[mt][r] + bb[r], 0.f);
    };

    auto p2 = [&](int s, f16x4 (&aH)[2]) {
#pragma unroll
        for (int ntp = 0; ntp < 2; ntp++) {
            f16x4 blo = __builtin_shufflevector(W2r[s][ntp], W2r[s][ntp], 0, 1, 2, 3);
            f16x4 bhi = __builtin_shufflevector(W2r[s][ntp], W2r[s][ntp], 4, 5, 6, 7);
#pragma unroll
            for (int mt = 0; mt < 2; mt++) {
                acc[mt][ntp * 2 + 0] = __builtin_amdgcn_mfma_f32_16x16x16f16(
                    aH[mt], blo, acc[mt][ntp * 2 + 0], 0, 0, 0);
                acc[mt][ntp * 2 + 1] = __builtin_amdgcn_mfma_f32_16x16x16f16(
                    aH[mt], bhi, acc[mt][ntp * 2 + 1], 0, 0, 0);
            }
        }
    };

    f16x4 aH[2];
    loadW(0, 0); loadW(1, 1); loadW(2, 2);
    {
        f32x4 h0[2] = {};
        p1(0, h0);
        cvt(h0, 0, aH);
    }
    for (int ub = 0; ub < 128; ub += 4) {
#pragma unroll
        for (int k = 0; k < 4; k++) {
            int u = ub + k;
            int lu = u + 3; if (lu > 127) lu = 127;
            loadW(lu, (k + 3) & 3);          // 3 chunks ahead
            f32x4 hn[2] = {};
            p1((k + 1) & 3, hn);             // phase1 for u+1
            p2(k & 3, aH);                   // phase2 for u
            cvt(hn, (k + 1) & 3, aH);        // aH for u+1
        }
    }

    // ---- epilogue: + b2 + residual(t1 bf16) -> LN2 -> bf16 ----
    float b2v[4], gv[4], bev[4];
#pragma unroll
    for (int nt = 0; nt < 4; nt++) {
        b2v[nt] = B2[nt * 16 + lm];
        gv[nt]  = g[nt * 16 + lm];
        bev[nt] = be[nt * 16 + lm];
    }
#pragma unroll
    for (int mt = 0; mt < 2; mt++)
#pragma unroll
        for (int r = 0; r < 4; r++) {
            int row = rowbase + mt * 16 + quad * 4 + r;
            float v[4]; float s = 0.f;
#pragma unroll
            for (int nt = 0; nt < 4; nt++) {
                v[nt] = acc[mt][nt][r] + b2v[nt] +
                        bf2f(T1b[(size_t)row * 64 + nt * 16 + lm]);
                s += v[nt];
            }
#pragma unroll
            for (int o = 8; o; o >>= 1) s += __shfl_xor(s, o, 64);
            float mu = s * 0.015625f;
            float q = 0.f;
#pragma unroll
            for (int nt = 0; nt < 4; nt++) { v[nt] -= mu; q += v[nt] * v[nt]; }
#pragma unroll
            for (int o = 8; o; o >>= 1) q += __shfl_xor(q, o, 64);
            float rstd = rsqrtf(q * 0.015625f + 1e-5f);
#pragma unroll
            for (int nt = 0; nt < 4; nt++)
                OutTb[(size_t)row * 64 + nt * 16 + lm] =
                    f2bf(gv[nt] * v[nt] * rstd + bev[nt]);
        }
}

// ---------------------------------------------------------------------------
__global__ __launch_bounds__(256) void ssum_k(const float* __restrict__ x,
                                              float* __restrict__ s)
{
    int gid = blockIdx.x * 256 + threadIdx.x;
    int b = gid / HW;
    int p = gid - b * HW;
    const float* xp = x + (size_t)b * 3 * HW + p;
    s[gid] = xp[0] + xp[HW] + xp[2 * HW];
}

// KPN fuse; filters in NE-padded layout [pix][16] (taps 0..8 valid)
__global__ __launch_bounds__(256) void kpn_k(const float* __restrict__ f,
                                             const float* __restrict__ s,
                                             float* __restrict__ out)
{
    int gid = blockIdx.x * 256 + threadIdx.x;
    int b = gid / HW;
    int p = gid - b * HW;
    int y = p / IW, x = p - y * IW;
    const float* fp = f + (size_t)gid * 16;
    const float* sp = s + (size_t)b * HW;
    float acc = 0.f;
#pragma unroll
    for (int u = 0; u < 3; u++) {
        int yy = y + u - 1;
        if ((unsigned)yy >= (unsigned)IW) continue;
#pragma unroll
        for (int v = 0; v < 3; v++) {
            int xx = x + v - 1;
            if ((unsigned)xx >= (unsigned)IW) continue;
            acc += fp[u * 3 + v] * sp[yy * IW + xx];
        }
    }
    out[gid] = acc;
}

// ---------------------------------------------------------------------------
// dec1: 1->64 conv, per-pixel thread, taps read once, NE bf16 out, relu
// ---------------------------------------------------------------------------
__global__ __launch_bounds__(256) void dec1_ne_k(const float* __restrict__ fused,
                                                 const float* __restrict__ w,
                                                 const float* __restrict__ bias,
                                                 ushort_t* __restrict__ out)
{
    int gid = blockIdx.x * 256 + threadIdx.x;  // < NPIX
    int b = gid >= HW;
    int p = gid - b * HW;
    int y = p / IW, xx = p - y * IW;
    const float* ip = fused + (size_t)b * HW;

    float v[9];
#pragma unroll
    for (int t = 0; t < 9; t++) {
        int yy = y + t / 3 - 1, xc = xx + t % 3 - 1;
        float tv = 0.f;
        if ((unsigned)yy < (unsigned)IW && (unsigned)xc < (unsigned)IW)
            tv = ip[yy * IW + xc];
        v[t] = tv;
    }
#pragma unroll
    for (int g = 0; g < 8; g++) {
        ushort8 o8;
#pragma unroll
        for (int i = 0; i < 8; i++) {
            int co = g * 8 + i;
            float a = bias[co];
            const float* wp = w + co * 9;
#pragma unroll
            for (int t = 0; t < 9; t++) a = fmaf(v[t], wp[t], a);
            o8[i] = f2bf(fmaxf(a, 0.f));
        }
        *reinterpret_cast<ushort8*>(out + (size_t)gid * 64 + g * 8) = o8;
    }
}

// ---------------------------------------------------------------------------
// dec2: 64->1 conv over NE bf16 input, sigmoid, fp32 out
// ---------------------------------------------------------------------------
__global__ __launch_bounds__(256) void dec2_ne_k(const ushort_t* __restrict__ D1,
                                                 const float* __restrict__ w,
                                                 const float* __restrict__ bias,
                                                 float* __restrict__ out)
{
    int gid = blockIdx.x * 256 + threadIdx.x;  // < NPIX
    int b = gid >= HW;
    int p = gid - b * HW;
    int y = p / IW, xx = p - y * IW;

    float acc = bias[0];
#pragma unroll
    for (int t = 0; t < 9; t++) {
        int yy = y + t / 3 - 1, xc = xx + t % 3 - 1;
        if ((unsigned)yy >= (unsigned)IW || (unsigned)xc >= (unsigned)IW) continue;
        const ushort_t* ip = D1 + (size_t)(gid + (t / 3 - 1) * IW + (t % 3 - 1)) * 64;
#pragma unroll
        for (int ks = 0; ks < 8; ks++) {
            float fv[8];
            b2f8(ip + ks * 8, fv);
#pragma unroll
            for (int i = 0; i < 8; i++)
                acc = fmaf(fv[i], w[(ks * 8 + i) * 9 + t], acc);
        }
    }
    out[gid] = 1.f / (1.f + __expf(-acc));
}

// ---------------------------------------------------------------------------
extern "C" void kernel_launch(void* const* d_in, const int* in_sizes, int n_in,
                              void* d_out, int out_size, void* d_ws, size_t ws_size,
                              hipStream_t stream)
{
    const float* x      = (const float*)d_in[0];
    const float* enc_w1 = (const float*)d_in[1];
    const float* enc_b1 = (const float*)d_in[2];
    const float* enc_w2 = (const float*)d_in[3];
    const float* enc_b2 = (const float*)d_in[4];
    const float* in_w   = (const float*)d_in[5];
    const float* in_b   = (const float*)d_in[6];
    const float* out_w  = (const float*)d_in[7];
    const float* out_b  = (const float*)d_in[8];
    const float* ln1_g  = (const float*)d_in[9];
    const float* ln1_b  = (const float*)d_in[10];
    const float* ffn_w1 = (const float*)d_in[11];
    const float* ffn_b1 = (const float*)d_in[12];
    const float* ffn_w2 = (const float*)d_in[13];
    const float* ffn_b2 = (const float*)d_in[14];
    const float* ln2_g  = (const float*)d_in[15];
    const float* ln2_b  = (const float*)d_in[16];
    const float* sf_w1  = (const float*)d_in[17];
    const float* sf_b1  = (const float*)d_in[18];
    const float* sf_w2  = (const float*)d_in[19];
    const float* sf_b2  = (const float*)d_in[20];
    const float* dec_w1 = (const float*)d_in[21];
    const float* dec_b1 = (const float*)d_in[22];
    const float* dec_w2 = (const float*)d_in[23];
    const float* dec_b2 = (const float*)d_in[24];

    float* ws = (float*)d_ws;
    const size_t SZ = (size_t)NPIX * 64;

    ushort_t* QKVb = (ushort_t*)(ws + 3 * SZ);             // 1.5 SZ floats
    ushort_t* ATb  = (ushort_t*)(ws + 9 * SZ / 2);         // 0.5 SZ
    ushort_t* E1b  = (ushort_t*)(ws + 5 * SZ);             // conv1 out / t1 bf16
    ushort_t* Tb   = (ushort_t*)(ws + 11 * SZ / 2);        // conv2 bf16 / t2 bf16
    ushort_t* wu   = (ushort_t*)(ws + 6 * SZ);             // weights
    ushort_t* in_wb  = wu;                                 // 12288
    ushort_t* out_wb = wu + 12288;                         // 4096
    ushort_t* w1b    = wu + 16384;                         // 131072
    _Float16* w2s    = (_Float16*)(wu + 147456);           // 131072 halves
    ushort_t* wc2    = wu + 278528;                        // 36864
    ushort_t* ws1    = wu + 315392;                        // 18432
    ushort_t* ws2    = wu + 333824;                        // 4608
    // late-stage scratch (QKV region dead after attention):
    float*    base3 = ws + 3 * SZ;
    ushort_t* s1b   = (ushort_t*)base3;                    // NPIX*32 bf16 (SZ/4 floats)
    float*    filtp = base3 + SZ / 4;                      // NPIX*16 f32 (SZ/4)
    float*    sbuf  = base3 + SZ / 2;                      // NPIX
    float*    fused = sbuf + NPIX;                         // NPIX
    ushort_t* D1b   = (ushort_t*)(base3 + SZ / 2 + 2 * (size_t)NPIX);  // NPIX*64 bf16

    // ---- merged weight prep ----
    prep_k<<<1322, 256, 0, stream>>>(in_w, in_wb, out_w, out_wb, ffn_w1, w1b,
                                     ffn_w2, w2s, enc_w2, wc2, sf_w1, ws1, sf_w2, ws2);

    // ---- encoder ----
    conv1_ne_k<<<392, 256, 0, stream>>>(x, enc_w1, enc_b1, E1b);
    neconv_k<2, 4, 64, 1, false, true><<<784, 256, 0, stream>>>(E1b, wc2, enc_b2, nullptr, Tb);
    // ---- transformer ----
    gemmQKV_k<<<1568, 256, 0, stream>>>(Tb, in_wb, in_b, QKVb);
    attn_k<<<784, 256, 0, stream>>>(QKVb, ATb);
    oproj_ln_k<<<1568, 256, 0, stream>>>(ATb, out_wb, out_b, Tb, ln1_g, ln1_b, E1b);
    ffn4_k<<<784, 256, 0, stream>>>(E1b, w1b, ffn_b1, w2s, ffn_b2, ln2_g, ln2_b, Tb);
    // ---- filter prediction ----
    neconv_k<2, 2, 32, 0, false, true><<<784, 256, 0, stream>>>(Tb, ws1, sf_b1, nullptr, s1b);
    neconv_k<1, 1, 9, 0, true, false><<<784, 256, 0, stream>>>(s1b, ws2, sf_b2, filtp, nullptr);
    // ---- KPN fuse ----
    ssum_k<<<392, 256, 0, stream>>>(x, sbuf);
    kpn_k<<<392, 256, 0, stream>>>(filtp, sbuf, fused);
    // ---- decoder (NE) ----
    dec1_ne_k<<<392, 256, 0, stream>>>(fused, dec_w1, dec_b1, D1b);
    dec2_ne_k<<<392, 256, 0, stream>>>(D1b, dec_w2, dec_b2, (float*)d_out);
}

// Round 6
// 420.277 us; speedup vs baseline: 3.7569x; 1.1423x over previous
//
#include <hip/hip_runtime.h>
#include <hip/hip_bf16.h>
#include <cstddef>

#define HW   50176
#define NPIX 100352
#define IW   224

typedef unsigned short ushort_t;
typedef __attribute__((ext_vector_type(8))) short bf16x8;
typedef __attribute__((ext_vector_type(8))) unsigned short ushort8;
typedef __attribute__((ext_vector_type(4))) float f32x4;
typedef __attribute__((ext_vector_type(4))) _Float16 f16x4;
typedef __attribute__((ext_vector_type(8))) _Float16 f16x8;

__device__ inline ushort_t f2bf(float f) {
    __hip_bfloat16 h = __float2bfloat16(f);
    return __builtin_bit_cast(ushort_t, h);
}
__device__ inline float bf2f(ushort_t u) {
    return __uint_as_float(((unsigned)u) << 16);
}
__device__ inline bf16x8 ldg8(const ushort_t* p) {
    return *reinterpret_cast<const bf16x8*>(p);
}
__device__ inline void b2f8(const ushort_t* p, float* f) {
    ushort8 v = *reinterpret_cast<const ushort8*>(p);
#pragma unroll
    for (int i = 0; i < 8; i++) f[i] = bf2f(v[i]);
}

// async global->LDS DMA, 16 B per lane; lds dest must be wave-uniform.
__device__ inline void dma16(const ushort_t* g, ushort_t* l) {
    __builtin_amdgcn_global_load_lds(
        (const __attribute__((address_space(1))) void*)g,
        (__attribute__((address_space(3))) void*)l, 16, 0, 0);
}

// ---------------------------------------------------------------------------
// single merged weight-prep kernel
// W1p: chunk-major padded image: chunk c (64 j), row jl stride 72 bf16,
//      chunk stride 6144 elements (12288 B = 3 DMA rounds of 4 KB).
// ---------------------------------------------------------------------------
__device__ inline void wswz_one(const float* __restrict__ w, ushort_t* __restrict__ out,
                                int idx, int Cout, int Cin)
{
    int ci = idx % Cin;
    int t  = (idx / Cin) % 9;
    int co = idx / (Cin * 9);
    out[idx] = (co < Cout) ? f2bf(w[((size_t)co * Cin + ci) * 9 + t]) : (ushort_t)0;
}

__global__ __launch_bounds__(256) void prep_k(
    const float* __restrict__ in_w,  ushort_t* __restrict__ in_wb,
    const float* __restrict__ out_w, ushort_t* __restrict__ out_wb,
    const float* __restrict__ w1,    ushort_t* __restrict__ w1p,
    const float* __restrict__ w2,    _Float16* __restrict__ w2s,
    const float* __restrict__ ec2,   ushort_t* __restrict__ wc2,
    const float* __restrict__ s1,    ushort_t* __restrict__ ws1,
    const float* __restrict__ s2,    ushort_t* __restrict__ ws2)
{
    int idx = blockIdx.x * 256 + threadIdx.x;
    if (idx < 12288) { in_wb[idx] = f2bf(in_w[idx]); return; }
    idx -= 12288;
    if (idx < 4096)  { out_wb[idx] = f2bf(out_w[idx]); return; }
    idx -= 4096;
    if (idx < 131072){
        // W1 padded-chunk layout
        int j = idx >> 6, e = idx & 63;
        int c = j >> 6, jl = j & 63;
        w1p[(size_t)c * 6144 + jl * 72 + e] = f2bf(w1[idx]);
        return;
    }
    idx -= 131072;
    if (idx < 131072){
        int h    = idx & 7;
        int lane = (idx >> 3) & 63;
        int cp   = idx >> 9;          // u*2 + ntp
        int ntp  = cp & 1;
        int u    = cp >> 1;
        int ntl  = h >> 2, jj = h & 3;
        int e2 = (ntp * 2 + ntl) * 16 + (lane & 15);
        int j  = u * 16 + (lane >> 4) * 4 + jj;
        w2s[idx] = (_Float16)w2[(size_t)e2 * 2048 + j];
        return;
    }
    idx -= 131072;
    if (idx < 36864) { wswz_one(ec2, wc2, idx, 64, 64); return; }
    idx -= 36864;
    if (idx < 18432) { wswz_one(s1, ws1, idx, 32, 64); return; }
    idx -= 18432;
    if (idx < 4608)  { wswz_one(s2, ws2, idx, 9, 32); return; }
}

// ---------------------------------------------------------------------------
// conv1: 3->64, per-pixel thread, writes NE bf16 [pix][64], relu
// ---------------------------------------------------------------------------
__global__ __launch_bounds__(256) void conv1_ne_k(const float* __restrict__ x,
                                                  const float* __restrict__ w,
                                                  const float* __restrict__ bias,
                                                  ushort_t* __restrict__ out)
{
    int gid = blockIdx.x * 256 + threadIdx.x;  // < NPIX
    int b = gid >= HW;
    int p = gid - b * HW;
    int y = p / IW, xx = p - y * IW;

    float v[27];
#pragma unroll
    for (int ci = 0; ci < 3; ci++) {
        const float* ip = x + ((size_t)(b * 3 + ci)) * HW;
#pragma unroll
        for (int t = 0; t < 9; t++) {
            int dy = t / 3 - 1, dx = t % 3 - 1;
            int yy = y + dy, xc = xx + dx;
            float tv = 0.f;
            if ((unsigned)yy < (unsigned)IW && (unsigned)xc < (unsigned)IW)
                tv = ip[yy * IW + xc];
            v[ci * 9 + t] = tv;
        }
    }
#pragma unroll
    for (int g = 0; g < 8; g++) {
        ushort8 o8;
#pragma unroll
        for (int i = 0; i < 8; i++) {
            int co = g * 8 + i;
            float a = bias[co];
            const float* wp = w + co * 27;
#pragma unroll
            for (int k = 0; k < 27; k++) a = fmaf(v[k], wp[k], a);
            o8[i] = f2bf(fmaxf(a, 0.f));
        }
        *reinterpret_cast<ushort8*>(out + (size_t)gid * 64 + g * 8) = o8;
    }
}

// ---------------------------------------------------------------------------
// NE-layout MFMA conv 3x3
// ---------------------------------------------------------------------------
template<int KS, int NT, int NC, int ACT, bool WF32, bool WB16>
__global__ __launch_bounds__(256) void neconv_k(
    const ushort_t* __restrict__ In, const ushort_t* __restrict__ Wsw,
    const float* __restrict__ bias, float* __restrict__ Of,
    ushort_t* __restrict__ Ob)
{
    const int CIN = KS * 32, LDO = NT * 16;
    int tid = threadIdx.x, wave = tid >> 6, lane = tid & 63;
    int lm = lane & 15, quad = lane >> 4;
    int m0 = blockIdx.x * 128 + wave * 32;

    int m[2], py[2], px[2];
#pragma unroll
    for (int mt = 0; mt < 2; mt++) {
        int mm = m0 + mt * 16 + lm;
        m[mt] = mm;
        int p = mm - (mm >= HW ? HW : 0);
        py[mt] = p / IW;
        px[mt] = p - py[mt] * IW;
    }

    f32x4 acc[2][NT] = {};
    bf16x8 zz = {};

#pragma unroll 3
    for (int t = 0; t < 9; t++) {
        int dy = t / 3 - 1, dx = t % 3 - 1;
        bf16x8 af[2][KS];
#pragma unroll
        for (int mt = 0; mt < 2; mt++) {
            bool ok = (unsigned)(py[mt] + dy) < (unsigned)IW &&
                      (unsigned)(px[mt] + dx) < (unsigned)IW;
            const ushort_t* ip = In + (size_t)(m[mt] + dy * IW + dx) * CIN + quad * 8;
#pragma unroll
            for (int ks = 0; ks < KS; ks++)
                af[mt][ks] = ok ? ldg8(ip + ks * 32) : zz;
        }
#pragma unroll
        for (int nt = 0; nt < NT; nt++) {
            const ushort_t* wp = Wsw + ((size_t)(nt * 16 + lm) * 9 + t) * CIN + quad * 8;
#pragma unroll
            for (int ks = 0; ks < KS; ks++) {
                bf16x8 bfv = ldg8(wp + ks * 32);
#pragma unroll
                for (int mt = 0; mt < 2; mt++)
                    acc[mt][nt] = __builtin_amdgcn_mfma_f32_16x16x32_bf16(
                        af[mt][ks], bfv, acc[mt][nt], 0, 0, 0);
            }
        }
    }

#pragma unroll
    for (int nt = 0; nt < NT; nt++) {
        int col = nt * 16 + lm;
        float bv = (col < NC) ? bias[col] : 0.f;
#pragma unroll
        for (int mt = 0; mt < 2; mt++)
#pragma unroll
            for (int r = 0; r < 4; r++) {
                int row = m0 + mt * 16 + quad * 4 + r;
                float v = acc[mt][nt][r] + bv;
                if (ACT) v = fmaxf(v, 0.f);
                if (WF32) Of[(size_t)row * LDO + col] = v;
                if (WB16) Ob[(size_t)row * LDO + col] = f2bf(v);
            }
    }
}

// ---------------------------------------------------------------------------
// qkv GEMM, one pass over all 192 cols (A read once). bf16 out.
// ---------------------------------------------------------------------------
__global__ __launch_bounds__(256) void gemmQKV_k(
    const ushort_t* __restrict__ Ab, const ushort_t* __restrict__ Wb,
    const float* __restrict__ bias, ushort_t* __restrict__ Cout)
{
    int tid = threadIdx.x, wave = tid >> 6, lane = tid & 63;
    int lm = lane & 15, quad = lane >> 4;
    int row0 = blockIdx.x * 64 + wave * 16;

    bf16x8 a[2];
#pragma unroll
    for (int ks = 0; ks < 2; ks++)
        a[ks] = ldg8(Ab + (size_t)(row0 + lm) * 64 + ks * 32 + quad * 8);

    f32x4 acc[12] = {};
#pragma unroll
    for (int nt = 0; nt < 12; nt++)
#pragma unroll
        for (int ks = 0; ks < 2; ks++) {
            bf16x8 b = ldg8(Wb + (size_t)(nt * 16 + lm) * 64 + ks * 32 + quad * 8);
            acc[nt] = __builtin_amdgcn_mfma_f32_16x16x32_bf16(a[ks], b, acc[nt], 0, 0, 0);
        }

#pragma unroll
    for (int nt = 0; nt < 12; nt++) {
        float bv = bias[nt * 16 + lm];
#pragma unroll
        for (int r = 0; r < 4; r++) {
            float v = acc[nt][r] + bv;
            Cout[(size_t)(row0 + quad * 4 + r) * 192 + nt * 16 + lm] = f2bf(v);
        }
    }
}

// ---------------------------------------------------------------------------
// out-proj + residual(bf16 Tb) + LN1 fused. Writes t1 bf16 only.
// ---------------------------------------------------------------------------
__global__ __launch_bounds__(256) void oproj_ln_k(
    const ushort_t* __restrict__ Ab, const ushort_t* __restrict__ Wb,
    const float* __restrict__ bias, const ushort_t* __restrict__ Res,
    const float* __restrict__ g, const float* __restrict__ be,
    ushort_t* __restrict__ Ob)
{
    int tid = threadIdx.x, wave = tid >> 6, lane = tid & 63;
    int lm = lane & 15, quad = lane >> 4;
    int row0 = blockIdx.x * 64 + wave * 16;

    bf16x8 a[2];
#pragma unroll
    for (int ks = 0; ks < 2; ks++)
        a[ks] = ldg8(Ab + (size_t)(row0 + lm) * 64 + ks * 32 + quad * 8);

    f32x4 acc[4] = {};
#pragma unroll
    for (int nt = 0; nt < 4; nt++)
#pragma unroll
        for (int ks = 0; ks < 2; ks++) {
            bf16x8 b = ldg8(Wb + (size_t)(nt * 16 + lm) * 64 + ks * 32 + quad * 8);
            acc[nt] = __builtin_amdgcn_mfma_f32_16x16x32_bf16(a[ks], b, acc[nt], 0, 0, 0);
        }

    float bv[4], gv[4], bev[4];
#pragma unroll
    for (int nt = 0; nt < 4; nt++) {
        bv[nt]  = bias[nt * 16 + lm];
        gv[nt]  = g[nt * 16 + lm];
        bev[nt] = be[nt * 16 + lm];
    }

#pragma unroll
    for (int r = 0; r < 4; r++) {
        int row = row0 + quad * 4 + r;
        float v[4]; float s = 0.f;
#pragma unroll
        for (int nt = 0; nt < 4; nt++) {
            v[nt] = acc[nt][r] + bv[nt] + bf2f(Res[(size_t)row * 64 + nt * 16 + lm]);
            s += v[nt];
        }
#pragma unroll
        for (int o = 8; o; o >>= 1) s += __shfl_xor(s, o, 64);
        float mu = s * 0.015625f;
        float q = 0.f;
#pragma unroll
        for (int nt = 0; nt < 4; nt++) { v[nt] -= mu; q += v[nt] * v[nt]; }
#pragma unroll
        for (int o = 8; o; o >>= 1) q += __shfl_xor(q, o, 64);
        float rstd = rsqrtf(q * 0.015625f + 1e-5f);
#pragma unroll
        for (int nt = 0; nt < 4; nt++)
            Ob[(size_t)row * 64 + nt * 16 + lm] = f2bf(gv[nt] * v[nt] * rstd + bev[nt]);
    }
}

// ---------------------------------------------------------------------------
// attention: per (n, h). S=2 -> 2x2 scores. bf16 in/out.
// ---------------------------------------------------------------------------
__global__ __launch_bounds__(256) void attn_k(const ushort_t* __restrict__ qkv,
                                              ushort_t* __restrict__ out)
{
    int gid = blockIdx.x * 256 + threadIdx.x;  // < HW*4
    int n = gid >> 2, h = gid & 3;
    const ushort_t* r0 = qkv + (size_t)n * 192 + h * 16;
    const ushort_t* r1 = qkv + ((size_t)HW + n) * 192 + h * 16;

    float q0[16], k0[16], v0[16], q1[16], k1[16], v1[16];
    b2f8(r0,       q0); b2f8(r0 + 8,   q0 + 8);
    b2f8(r0 + 64,  k0); b2f8(r0 + 72,  k0 + 8);
    b2f8(r0 + 128, v0); b2f8(r0 + 136, v0 + 8);
    b2f8(r1,       q1); b2f8(r1 + 8,   q1 + 8);
    b2f8(r1 + 64,  k1); b2f8(r1 + 72,  k1 + 8);
    b2f8(r1 + 128, v1); b2f8(r1 + 136, v1 + 8);

    float s00 = 0, s01 = 0, s10 = 0, s11 = 0;
#pragma unroll
    for (int d = 0; d < 16; d++) {
        s00 += q0[d] * k0[d]; s01 += q0[d] * k1[d];
        s10 += q1[d] * k0[d]; s11 += q1[d] * k1[d];
    }
    s00 *= 0.25f; s01 *= 0.25f; s10 *= 0.25f; s11 *= 0.25f;

    float m0 = fmaxf(s00, s01);
    float e00 = __expf(s00 - m0), e01 = __expf(s01 - m0);
    float i0 = 1.f / (e00 + e01);
    float p00 = e00 * i0, p01 = e01 * i0;

    float m1 = fmaxf(s10, s11);
    float e10 = __expf(s10 - m1), e11 = __expf(s11 - m1);
    float i1 = 1.f / (e10 + e11);
    float p10 = e10 * i1, p11 = e11 * i1;

    ushort_t* o0 = out + (size_t)n * 64 + h * 16;
    ushort_t* o1 = out + ((size_t)HW + n) * 64 + h * 16;
#pragma unroll
    for (int c = 0; c < 2; c++) {
        ushort8 a0v, a1v;
#pragma unroll
        for (int i = 0; i < 8; i++) {
            int d = c * 8 + i;
            a0v[i] = f2bf(p00 * v0[d] + p01 * v1[d]);
            a1v[i] = f2bf(p10 * v0[d] + p11 * v1[d]);
        }
        *reinterpret_cast<ushort8*>(o0 + c * 8) = a0v;
        *reinterpret_cast<ushort8*>(o1 + c * 8) = a1v;
    }
}

// ---------------------------------------------------------------------------
// FFN v5: weights staged per 64-hidden chunk in LDS (shared by all 4 waves),
// double-buffered async DMA, one barrier/chunk (prefetch issued AFTER the
// barrier so the vmcnt drain only covers the already-landed current chunk).
// mt=2 (32 rows/wave, 128/block, 784 blocks). Fused bf16 residual + LN2.
// ---------------------------------------------------------------------------
__global__ __launch_bounds__(256) void ffn5_k(
    const ushort_t* __restrict__ T1b,
    const ushort_t* __restrict__ W1p, const float* __restrict__ B1,
    const _Float16* __restrict__ W2s, const float* __restrict__ B2,
    const float* __restrict__ g, const float* __restrict__ be,
    ushort_t* __restrict__ OutTb)
{
    __shared__ ushort_t W1lds[2][6144];   // rows stride 72 bf16, 12288 B each
    __shared__ ushort_t W2lds[2][4096];   // f16 bits, 8192 B each

    int tid = threadIdx.x, wave = tid >> 6, lane = tid & 63;
    int lm = lane & 15, quad = lane >> 4;
    int rowbase = blockIdx.x * 128 + wave * 32;

    bf16x8 Bt[2][2];
#pragma unroll
    for (int mt = 0; mt < 2; mt++)
#pragma unroll
        for (int ks = 0; ks < 2; ks++)
            Bt[mt][ks] = ldg8(T1b + (size_t)(rowbase + mt * 16 + lm) * 64 + ks * 32 + quad * 8);

    f32x4 acc[2][4] = {};

    auto dma_chunk = [&](int c, int pb) {
        const ushort_t* g1 = W1p + (size_t)c * 6144;
#pragma unroll
        for (int r = 0; r < 3; r++)
            dma16(g1 + (r * 4 + wave) * 512 + lane * 8,
                  &W1lds[pb][(r * 4 + wave) * 512]);
        const ushort_t* g2 = (const ushort_t*)(W2s + (size_t)c * 4096);
#pragma unroll
        for (int r = 0; r < 2; r++)
            dma16(g2 + (r * 4 + wave) * 512 + lane * 8,
                  &W2lds[pb][(r * 4 + wave) * 512]);
    };

    dma_chunk(0, 0);

    for (int c = 0; c < 32; c++) {
        int pb = c & 1;
        __syncthreads();                    // drains chunk-c DMA; syncs buffer reuse
        if (c + 1 < 32) dma_chunk(c + 1, pb ^ 1);

        const ushort_t* w1l = &W1lds[pb][0];
        const ushort_t* w2l = &W2lds[pb][0];

        bf16x8 w1r[2][2];
        f16x8  w2r[2][2];
        float4 b1r[2];

        auto ldfrag = [&](int ul, int s) {
#pragma unroll
            for (int ks = 0; ks < 2; ks++)
                w1r[s][ks] = *reinterpret_cast<const bf16x8*>(
                    &w1l[(ul * 16 + lm) * 72 + ks * 32 + quad * 8]);
#pragma unroll
            for (int ntp = 0; ntp < 2; ntp++)
                w2r[s][ntp] = *reinterpret_cast<const f16x8*>(
                    &w2l[((ul * 2 + ntp) * 64 + lane) * 8]);
            b1r[s] = *reinterpret_cast<const float4*>(B1 + (c * 4 + ul) * 16 + quad * 4);
        };

        auto p1 = [&](int s, f32x4 (&h)[2]) {
#pragma unroll
            for (int ks = 0; ks < 2; ks++)
#pragma unroll
                for (int mt = 0; mt < 2; mt++)
                    h[mt] = __builtin_amdgcn_mfma_f32_16x16x32_bf16(
                        w1r[s][ks], Bt[mt][ks], h[mt], 0, 0, 0);
        };

        auto cvt = [&](f32x4 (&h)[2], int s, f16x4 (&aH)[2]) {
            float bb[4] = {b1r[s].x, b1r[s].y, b1r[s].z, b1r[s].w};
#pragma unroll
            for (int mt = 0; mt < 2; mt++)
#pragma unroll
                for (int r = 0; r < 4; r++)
                    aH[mt][r] = (_Float16)fmaxf(h[mt][r] + bb[r], 0.f);
        };

        auto p2 = [&](int s, f16x4 (&aH)[2]) {
#pragma unroll
            for (int ntp = 0; ntp < 2; ntp++) {
                f16x4 blo = __builtin_shufflevector(w2r[s][ntp], w2r[s][ntp], 0, 1, 2, 3);
                f16x4 bhi = __builtin_shufflevector(w2r[s][ntp], w2r[s][ntp], 4, 5, 6, 7);
#pragma unroll
                for (int mt = 0; mt < 2; mt++) {
                    acc[mt][ntp * 2 + 0] = __builtin_amdgcn_mfma_f32_16x16x16f16(
                        aH[mt], blo, acc[mt][ntp * 2 + 0], 0, 0, 0);
                    acc[mt][ntp * 2 + 1] = __builtin_amdgcn_mfma_f32_16x16x16f16(
                        aH[mt], bhi, acc[mt][ntp * 2 + 1], 0, 0, 0);
                }
            }
        };

        f16x4 aH[2];
        ldfrag(0, 0);
        {
            f32x4 h0[2] = {};
            p1(0, h0);
            cvt(h0, 0, aH);
        }
#pragma unroll
        for (int ul = 0; ul < 4; ul++) {
            int cur = ul & 1, nxt = cur ^ 1;
            if (ul < 3) ldfrag(ul + 1, nxt);
            f32x4 hn[2] = {};
            if (ul < 3) p1(nxt, hn);
            p2(cur, aH);
            if (ul < 3) cvt(hn, nxt, aH);
        }
    }

    // ---- epilogue: + b2 + residual(t1 bf16) -> LN2 -> bf16 ----
    float b2v[4], gv[4], bev[4];
#pragma unroll
    for (int nt = 0; nt < 4; nt++) {
        b2v[nt] = B2[nt * 16 + lm];
        gv[nt]  = g[nt * 16 + lm];
        bev[nt] = be[nt * 16 + lm];
    }
#pragma unroll
    for (int mt = 0; mt < 2; mt++)
#pragma unroll
        for (int r = 0; r < 4; r++) {
            int row = rowbase + mt * 16 + quad * 4 + r;
            float v[4]; float s = 0.f;
#pragma unroll
            for (int nt = 0; nt < 4; nt++) {
                v[nt] = acc[mt][nt][r] + b2v[nt] +
                        bf2f(T1b[(size_t)row * 64 + nt * 16 + lm]);
                s += v[nt];
            }
#pragma unroll
            for (int o = 8; o; o >>= 1) s += __shfl_xor(s, o, 64);
            float mu = s * 0.015625f;
            float q = 0.f;
#pragma unroll
            for (int nt = 0; nt < 4; nt++) { v[nt] -= mu; q += v[nt] * v[nt]; }
#pragma unroll
            for (int o = 8; o; o >>= 1) q += __shfl_xor(q, o, 64);
            float rstd = rsqrtf(q * 0.015625f + 1e-5f);
#pragma unroll
            for (int nt = 0; nt < 4; nt++)
                OutTb[(size_t)row * 64 + nt * 16 + lm] =
                    f2bf(gv[nt] * v[nt] * rstd + bev[nt]);
        }
}

// ---------------------------------------------------------------------------
__global__ __launch_bounds__(256) void ssum_k(const float* __restrict__ x,
                                              float* __restrict__ s)
{
    int gid = blockIdx.x * 256 + threadIdx.x;
    int b = gid / HW;
    int p = gid - b * HW;
    const float* xp = x + (size_t)b * 3 * HW + p;
    s[gid] = xp[0] + xp[HW] + xp[2 * HW];
}

// KPN fuse; filters in NE-padded layout [pix][16] (taps 0..8 valid)
__global__ __launch_bounds__(256) void kpn_k(const float* __restrict__ f,
                                             const float* __restrict__ s,
                                             float* __restrict__ out)
{
    int gid = blockIdx.x * 256 + threadIdx.x;
    int b = gid / HW;
    int p = gid - b * HW;
    int y = p / IW, x = p - y * IW;
    const float* fp = f + (size_t)gid * 16;
    const float* sp = s + (size_t)b * HW;
    float acc = 0.f;
#pragma unroll
    for (int u = 0; u < 3; u++) {
        int yy = y + u - 1;
        if ((unsigned)yy >= (unsigned)IW) continue;
#pragma unroll
        for (int v = 0; v < 3; v++) {
            int xx = x + v - 1;
            if ((unsigned)xx >= (unsigned)IW) continue;
            acc += fp[u * 3 + v] * sp[yy * IW + xx];
        }
    }
    out[gid] = acc;
}

// ---------------------------------------------------------------------------
// dec1: 1->64 conv, per-pixel thread, taps read once, NE bf16 out, relu
// ---------------------------------------------------------------------------
__global__ __launch_bounds__(256) void dec1_ne_k(const float* __restrict__ fused,
                                                 const float* __restrict__ w,
                                                 const float* __restrict__ bias,
                                                 ushort_t* __restrict__ out)
{
    int gid = blockIdx.x * 256 + threadIdx.x;  // < NPIX
    int b = gid >= HW;
    int p = gid - b * HW;
    int y = p / IW, xx = p - y * IW;
    const float* ip = fused + (size_t)b * HW;

    float v[9];
#pragma unroll
    for (int t = 0; t < 9; t++) {
        int yy = y + t / 3 - 1, xc = xx + t % 3 - 1;
        float tv = 0.f;
        if ((unsigned)yy < (unsigned)IW && (unsigned)xc < (unsigned)IW)
            tv = ip[yy * IW + xc];
        v[t] = tv;
    }
#pragma unroll
    for (int g = 0; g < 8; g++) {
        ushort8 o8;
#pragma unroll
        for (int i = 0; i < 8; i++) {
            int co = g * 8 + i;
            float a = bias[co];
            const float* wp = w + co * 9;
#pragma unroll
            for (int t = 0; t < 9; t++) a = fmaf(v[t], wp[t], a);
            o8[i] = f2bf(fmaxf(a, 0.f));
        }
        *reinterpret_cast<ushort8*>(out + (size_t)gid * 64 + g * 8) = o8;
    }
}

// ---------------------------------------------------------------------------
// dec2: 64->1 conv over NE bf16 input, sigmoid, fp32 out
// ---------------------------------------------------------------------------
__global__ __launch_bounds__(256) void dec2_ne_k(const ushort_t* __restrict__ D1,
                                                 const float* __restrict__ w,
                                                 const float* __restrict__ bias,
                                                 float* __restrict__ out)
{
    int gid = blockIdx.x * 256 + threadIdx.x;  // < NPIX
    int b = gid >= HW;
    int p = gid - b * HW;
    int y = p / IW, xx = p - y * IW;

    float acc = bias[0];
#pragma unroll
    for (int t = 0; t < 9; t++) {
        int yy = y + t / 3 - 1, xc = xx + t % 3 - 1;
        if ((unsigned)yy >= (unsigned)IW || (unsigned)xc >= (unsigned)IW) continue;
        const ushort_t* ip = D1 + (size_t)(gid + (t / 3 - 1) * IW + (t % 3 - 1)) * 64;
#pragma unroll
        for (int ks = 0; ks < 8; ks++) {
            float fv[8];
            b2f8(ip + ks * 8, fv);
#pragma unroll
            for (int i = 0; i < 8; i++)
                acc = fmaf(fv[i], w[(ks * 8 + i) * 9 + t], acc);
        }
    }
    out[gid] = 1.f / (1.f + __expf(-acc));
}

// ---------------------------------------------------------------------------
extern "C" void kernel_launch(void* const* d_in, const int* in_sizes, int n_in,
                              void* d_out, int out_size, void* d_ws, size_t ws_size,
                              hipStream_t stream)
{
    const float* x      = (const float*)d_in[0];
    const float* enc_w1 = (const float*)d_in[1];
    const float* enc_b1 = (const float*)d_in[2];
    const float* enc_w2 = (const float*)d_in[3];
    const float* enc_b2 = (const float*)d_in[4];
    const float* in_w   = (const float*)d_in[5];
    const float* in_b   = (const float*)d_in[6];
    const float* out_w  = (const float*)d_in[7];
    const float* out_b  = (const float*)d_in[8];
    const float* ln1_g  = (const float*)d_in[9];
    const float* ln1_b  = (const float*)d_in[10];
    const float* ffn_w1 = (const float*)d_in[11];
    const float* ffn_b1 = (const float*)d_in[12];
    const float* ffn_w2 = (const float*)d_in[13];
    const float* ffn_b2 = (const float*)d_in[14];
    const float* ln2_g  = (const float*)d_in[15];
    const float* ln2_b  = (const float*)d_in[16];
    const float* sf_w1  = (const float*)d_in[17];
    const float* sf_b1  = (const float*)d_in[18];
    const float* sf_w2  = (const float*)d_in[19];
    const float* sf_b2  = (const float*)d_in[20];
    const float* dec_w1 = (const float*)d_in[21];
    const float* dec_b1 = (const float*)d_in[22];
    const float* dec_w2 = (const float*)d_in[23];
    const float* dec_b2 = (const float*)d_in[24];

    float* ws = (float*)d_ws;
    const size_t SZ = (size_t)NPIX * 64;

    ushort_t* QKVb = (ushort_t*)(ws + 3 * SZ);             // 1.5 SZ floats
    ushort_t* ATb  = (ushort_t*)(ws + 9 * SZ / 2);         // 0.5 SZ
    ushort_t* E1b  = (ushort_t*)(ws + 5 * SZ);             // conv1 out / t1 bf16
    ushort_t* Tb   = (ushort_t*)(ws + 11 * SZ / 2);        // conv2 bf16 / t2 bf16
    ushort_t* wu   = (ushort_t*)(ws + 6 * SZ);             // weights
    ushort_t* in_wb  = wu;                                 // 12288
    ushort_t* out_wb = wu + 12288;                         // 4096
    ushort_t* w1p    = wu + 16384;                         // 196608 (padded chunks)
    _Float16* w2s    = (_Float16*)(wu + 212992);           // 131072 halves
    ushort_t* wc2    = wu + 344064;                        // 36864
    ushort_t* ws1    = wu + 380928;                        // 18432
    ushort_t* ws2    = wu + 399360;                        // 4608
    // late-stage scratch (QKV region dead after attention):
    float*    base3 = ws + 3 * SZ;
    ushort_t* s1b   = (ushort_t*)base3;                    // NPIX*32 bf16 (SZ/4 floats)
    float*    filtp = base3 + SZ / 4;                      // NPIX*16 f32 (SZ/4)
    float*    sbuf  = base3 + SZ / 2;                      // NPIX
    float*    fused = sbuf + NPIX;                         // NPIX
    ushort_t* D1b   = (ushort_t*)(base3 + SZ / 2 + 2 * (size_t)NPIX);  // NPIX*64 bf16

    // ---- merged weight prep ----
    prep_k<<<1322, 256, 0, stream>>>(in_w, in_wb, out_w, out_wb, ffn_w1, w1p,
                                     ffn_w2, w2s, enc_w2, wc2, sf_w1, ws1, sf_w2, ws2);

    // ---- encoder ----
    conv1_ne_k<<<392, 256, 0, stream>>>(x, enc_w1, enc_b1, E1b);
    neconv_k<2, 4, 64, 1, false, true><<<784, 256, 0, stream>>>(E1b, wc2, enc_b2, nullptr, Tb);
    // ---- transformer ----
    gemmQKV_k<<<1568, 256, 0, stream>>>(Tb, in_wb, in_b, QKVb);
    attn_k<<<784, 256, 0, stream>>>(QKVb, ATb);
    oproj_ln_k<<<1568, 256, 0, stream>>>(ATb, out_wb, out_b, Tb, ln1_g, ln1_b, E1b);
    ffn5_k<<<784, 256, 0, stream>>>(E1b, w1p, ffn_b1, w2s, ffn_b2, ln2_g, ln2_b, Tb);
    // ---- filter prediction ----
    neconv_k<2, 2, 32, 0, false, true><<<784, 256, 0, stream>>>(Tb, ws1, sf_b1, nullptr, s1b);
    neconv_k<1, 1, 9, 0, true, false><<<784, 256, 0, stream>>>(s1b, ws2, sf_b2, filtp, nullptr);
    // ---- KPN fuse ----
    ssum_k<<<392, 256, 0, stream>>>(x, sbuf);
    kpn_k<<<392, 256, 0, stream>>>(filtp, sbuf, fused);
    // ---- decoder (NE) ----
    dec1_ne_k<<<392, 256, 0, stream>>>(fused, dec_w1, dec_b1, D1b);
    dec2_ne_k<<<392, 256, 0, stream>>>(D1b, dec_w2, dec_b2, (float*)d_out);
}

// Round 8
// 411.896 us; speedup vs baseline: 3.8333x; 1.0203x over previous
//
#include <hip/hip_runtime.h>
#include <hip/hip_bf16.h>
#include <cstddef>

#define HW   50176
#define NPIX 100352
#define IW   224

typedef unsigned short ushort_t;
typedef __attribute__((ext_vector_type(8))) short bf16x8;
typedef __attribute__((ext_vector_type(8))) unsigned short ushort8;
typedef __attribute__((ext_vector_type(4))) float f32x4;
typedef __attribute__((ext_vector_type(2))) _Float16 f16x2;
typedef __attribute__((ext_vector_type(4))) _Float16 f16x4;
typedef __attribute__((ext_vector_type(8))) _Float16 f16x8;

__device__ inline ushort_t f2bf(float f) {
    __hip_bfloat16 h = __float2bfloat16(f);
    return __builtin_bit_cast(ushort_t, h);
}
__device__ inline float bf2f(ushort_t u) {
    return __uint_as_float(((unsigned)u) << 16);
}
__device__ inline bf16x8 ldg8(const ushort_t* p) {
    return *reinterpret_cast<const bf16x8*>(p);
}
__device__ inline void b2f8(const ushort_t* p, float* f) {
    ushort8 v = *reinterpret_cast<const ushort8*>(p);
#pragma unroll
    for (int i = 0; i < 8; i++) f[i] = bf2f(v[i]);
}
__device__ inline f16x2 pk16(float a, float b) {
    return __builtin_bit_cast(f16x2, __builtin_amdgcn_cvt_pkrtz(a, b));
}

// async global->LDS DMA, 16 B per lane; lds dest must be wave-uniform.
__device__ inline void dma16(const ushort_t* g, ushort_t* l) {
    __builtin_amdgcn_global_load_lds(
        (const __attribute__((address_space(1))) void*)g,
        (__attribute__((address_space(3))) void*)l, 16, 0, 0);
}

// ---------------------------------------------------------------------------
// single merged weight-prep kernel
// W1p: chunk-major padded image: chunk c (64 j), row jl stride 72 bf16.
// W2s: paired-K f16 layout for mfma_f32_16x16x32_f16 phase2:
//      idx = (((c*2+p)*4+nt)*64+lane)*8+j ;
//      hidden = c*64 + p*32 + (j<4 ? quad*4+j : 16+quad*4+(j-4)), quad=lane>>4
// ---------------------------------------------------------------------------
__device__ inline void wswz_one(const float* __restrict__ w, ushort_t* __restrict__ out,
                                int idx, int Cout, int Cin)
{
    int ci = idx % Cin;
    int t  = (idx / Cin) % 9;
    int co = idx / (Cin * 9);
    out[idx] = (co < Cout) ? f2bf(w[((size_t)co * Cin + ci) * 9 + t]) : (ushort_t)0;
}

__global__ __launch_bounds__(256) void prep_k(
    const float* __restrict__ in_w,  ushort_t* __restrict__ in_wb,
    const float* __restrict__ out_w, ushort_t* __restrict__ out_wb,
    const float* __restrict__ w1,    ushort_t* __restrict__ w1p,
    const float* __restrict__ w2,    _Float16* __restrict__ w2s,
    const float* __restrict__ ec2,   ushort_t* __restrict__ wc2,
    const float* __restrict__ s1,    ushort_t* __restrict__ ws1,
    const float* __restrict__ s2,    ushort_t* __restrict__ ws2)
{
    int idx = blockIdx.x * 256 + threadIdx.x;
    if (idx < 12288) { in_wb[idx] = f2bf(in_w[idx]); return; }
    idx -= 12288;
    if (idx < 4096)  { out_wb[idx] = f2bf(out_w[idx]); return; }
    idx -= 4096;
    if (idx < 131072){
        // W1 padded-chunk layout
        int j = idx >> 6, e = idx & 63;
        int c = j >> 6, jl = j & 63;
        w1p[(size_t)c * 6144 + jl * 72 + e] = f2bf(w1[idx]);
        return;
    }
    idx -= 131072;
    if (idx < 131072){
        int j    = idx & 7;
        int lane = (idx >> 3) & 63;
        int rest = idx >> 9;          // (c*2+p)*4+nt
        int nt   = rest & 3;
        int cp   = rest >> 2;         // c*2+p
        int p    = cp & 1;
        int c    = cp >> 1;
        int quad = lane >> 4;
        int e2   = nt * 16 + (lane & 15);
        int hl   = (j < 4) ? (quad * 4 + j) : (16 + quad * 4 + (j - 4));
        int hidden = c * 64 + p * 32 + hl;
        w2s[idx] = (_Float16)w2[(size_t)e2 * 2048 + hidden];
        return;
    }
    idx -= 131072;
    if (idx < 36864) { wswz_one(ec2, wc2, idx, 64, 64); return; }
    idx -= 36864;
    if (idx < 18432) { wswz_one(s1, ws1, idx, 32, 64); return; }
    idx -= 18432;
    if (idx < 4608)  { wswz_one(s2, ws2, idx, 9, 32); return; }
}

// ---------------------------------------------------------------------------
// conv1: 3->64, per-pixel thread, writes NE bf16 [pix][64], relu
// ---------------------------------------------------------------------------
__global__ __launch_bounds__(256) void conv1_ne_k(const float* __restrict__ x,
                                                  const float* __restrict__ w,
                                                  const float* __restrict__ bias,
                                                  ushort_t* __restrict__ out)
{
    int gid = blockIdx.x * 256 + threadIdx.x;  // < NPIX
    int b = gid >= HW;
    int p = gid - b * HW;
    int y = p / IW, xx = p - y * IW;

    float v[27];
#pragma unroll
    for (int ci = 0; ci < 3; ci++) {
        const float* ip = x + ((size_t)(b * 3 + ci)) * HW;
#pragma unroll
        for (int t = 0; t < 9; t++) {
            int dy = t / 3 - 1, dx = t % 3 - 1;
            int yy = y + dy, xc = xx + dx;
            float tv = 0.f;
            if ((unsigned)yy < (unsigned)IW && (unsigned)xc < (unsigned)IW)
                tv = ip[yy * IW + xc];
            v[ci * 9 + t] = tv;
        }
    }
#pragma unroll
    for (int g = 0; g < 8; g++) {
        ushort8 o8;
#pragma unroll
        for (int i = 0; i < 8; i++) {
            int co = g * 8 + i;
            float a = bias[co];
            const float* wp = w + co * 27;
#pragma unroll
            for (int k = 0; k < 27; k++) a = fmaf(v[k], wp[k], a);
            o8[i] = f2bf(fmaxf(a, 0.f));
        }
        *reinterpret_cast<ushort8*>(out + (size_t)gid * 64 + g * 8) = o8;
    }
}

// ---------------------------------------------------------------------------
// NE-layout MFMA conv 3x3
// ---------------------------------------------------------------------------
template<int KS, int NT, int NC, int ACT, bool WF32, bool WB16>
__global__ __launch_bounds__(256) void neconv_k(
    const ushort_t* __restrict__ In, const ushort_t* __restrict__ Wsw,
    const float* __restrict__ bias, float* __restrict__ Of,
    ushort_t* __restrict__ Ob)
{
    const int CIN = KS * 32, LDO = NT * 16;
    int tid = threadIdx.x, wave = tid >> 6, lane = tid & 63;
    int lm = lane & 15, quad = lane >> 4;
    int m0 = blockIdx.x * 128 + wave * 32;

    int m[2], py[2], px[2];
#pragma unroll
    for (int mt = 0; mt < 2; mt++) {
        int mm = m0 + mt * 16 + lm;
        m[mt] = mm;
        int p = mm - (mm >= HW ? HW : 0);
        py[mt] = p / IW;
        px[mt] = p - py[mt] * IW;
    }

    f32x4 acc[2][NT] = {};
    bf16x8 zz = {};

#pragma unroll 3
    for (int t = 0; t < 9; t++) {
        int dy = t / 3 - 1, dx = t % 3 - 1;
        bf16x8 af[2][KS];
#pragma unroll
        for (int mt = 0; mt < 2; mt++) {
            bool ok = (unsigned)(py[mt] + dy) < (unsigned)IW &&
                      (unsigned)(px[mt] + dx) < (unsigned)IW;
            const ushort_t* ip = In + (size_t)(m[mt] + dy * IW + dx) * CIN + quad * 8;
#pragma unroll
            for (int ks = 0; ks < KS; ks++)
                af[mt][ks] = ok ? ldg8(ip + ks * 32) : zz;
        }
#pragma unroll
        for (int nt = 0; nt < NT; nt++) {
            const ushort_t* wp = Wsw + ((size_t)(nt * 16 + lm) * 9 + t) * CIN + quad * 8;
#pragma unroll
            for (int ks = 0; ks < KS; ks++) {
                bf16x8 bfv = ldg8(wp + ks * 32);
#pragma unroll
                for (int mt = 0; mt < 2; mt++)
                    acc[mt][nt] = __builtin_amdgcn_mfma_f32_16x16x32_bf16(
                        af[mt][ks], bfv, acc[mt][nt], 0, 0, 0);
            }
        }
    }

#pragma unroll
    for (int nt = 0; nt < NT; nt++) {
        int col = nt * 16 + lm;
        float bv = (col < NC) ? bias[col] : 0.f;
#pragma unroll
        for (int mt = 0; mt < 2; mt++)
#pragma unroll
            for (int r = 0; r < 4; r++) {
                int row = m0 + mt * 16 + quad * 4 + r;
                float v = acc[mt][nt][r] + bv;
                if (ACT) v = fmaxf(v, 0.f);
                if (WF32) Of[(size_t)row * LDO + col] = v;
                if (WB16) Ob[(size_t)row * LDO + col] = f2bf(v);
            }
    }
}

// ---------------------------------------------------------------------------
// fused transformer front: qkv GEMM -> attention (S=2) -> out-proj + residual
// + LN1, all through LDS. Block = 64 pixels x both batches = 128 rows.
// LDS Q: 128 rows x 200 cols bf16 (192 qkv + pad). AT overwrites Q's q-slots
// (each (pixel,head) slice is owned by exactly one thread).
// ---------------------------------------------------------------------------
__global__ __launch_bounds__(256) void xformer_k(
    const ushort_t* __restrict__ Tb, const ushort_t* __restrict__ Wqkv,
    const float* __restrict__ Bqkv, const ushort_t* __restrict__ Wo,
    const float* __restrict__ Bo, const float* __restrict__ g,
    const float* __restrict__ be, ushort_t* __restrict__ T1b)
{
    __shared__ ushort_t Q[128 * 200];
    int tid = threadIdx.x, wave = tid >> 6, lane = tid & 63;
    int lm = lane & 15, quad = lane >> 4;
    int n0 = blockIdx.x * 64;

    // ---- phase A: qkv projection into LDS ----
#pragma unroll
    for (int mt = 0; mt < 2; mt++) {
        int grow = (mt == 0 ? n0 : HW + n0) + wave * 16;
        bf16x8 a[2];
#pragma unroll
        for (int ks = 0; ks < 2; ks++)
            a[ks] = ldg8(Tb + (size_t)(grow + lm) * 64 + ks * 32 + quad * 8);
        f32x4 acc[12] = {};
#pragma unroll
        for (int nt = 0; nt < 12; nt++)
#pragma unroll
            for (int ks = 0; ks < 2; ks++) {
                bf16x8 b = ldg8(Wqkv + (size_t)(nt * 16 + lm) * 64 + ks * 32 + quad * 8);
                acc[nt] = __builtin_amdgcn_mfma_f32_16x16x32_bf16(a[ks], b, acc[nt], 0, 0, 0);
            }
        int lrow = mt * 64 + wave * 16 + quad * 4;
#pragma unroll
        for (int nt = 0; nt < 12; nt++) {
            float bb = Bqkv[nt * 16 + lm];
#pragma unroll
            for (int r = 0; r < 4; r++)
                Q[(lrow + r) * 200 + nt * 16 + lm] = f2bf(acc[nt][r] + bb);
        }
    }
    __syncthreads();

    // ---- phase B: attention (per pixel x head) ----
    {
        int px = tid >> 2, h = tid & 3;
        ushort_t* r0 = &Q[px * 200 + h * 16];
        ushort_t* r1 = &Q[(64 + px) * 200 + h * 16];

        float q0[16], k0[16], v0[16], q1[16], k1[16], v1[16];
        b2f8(r0,       q0); b2f8(r0 + 8,   q0 + 8);
        b2f8(r0 + 64,  k0); b2f8(r0 + 72,  k0 + 8);
        b2f8(r0 + 128, v0); b2f8(r0 + 136, v0 + 8);
        b2f8(r1,       q1); b2f8(r1 + 8,   q1 + 8);
        b2f8(r1 + 64,  k1); b2f8(r1 + 72,  k1 + 8);
        b2f8(r1 + 128, v1); b2f8(r1 + 136, v1 + 8);

        float s00 = 0, s01 = 0, s10 = 0, s11 = 0;
#pragma unroll
        for (int d = 0; d < 16; d++) {
            s00 += q0[d] * k0[d]; s01 += q0[d] * k1[d];
            s10 += q1[d] * k0[d]; s11 += q1[d] * k1[d];
        }
        s00 *= 0.25f; s01 *= 0.25f; s10 *= 0.25f; s11 *= 0.25f;

        float m0 = fmaxf(s00, s01);
        float e00 = __expf(s00 - m0), e01 = __expf(s01 - m0);
        float i0 = 1.f / (e00 + e01);
        float p00 = e00 * i0, p01 = e01 * i0;

        float m1 = fmaxf(s10, s11);
        float e10 = __expf(s10 - m1), e11 = __expf(s11 - m1);
        float i1 = 1.f / (e10 + e11);
        float p10 = e10 * i1, p11 = e11 * i1;

#pragma unroll
        for (int c = 0; c < 2; c++) {
            ushort8 a0v, a1v;
#pragma unroll
            for (int i = 0; i < 8; i++) {
                int d = c * 8 + i;
                a0v[i] = f2bf(p00 * v0[d] + p01 * v1[d]);
                a1v[i] = f2bf(p10 * v0[d] + p11 * v1[d]);
            }
            *reinterpret_cast<ushort8*>(r0 + c * 8) = a0v;
            *reinterpret_cast<ushort8*>(r1 + c * 8) = a1v;
        }
    }
    __syncthreads();

    // ---- phase C: out-proj + residual + LN1 -> t1 bf16 ----
#pragma unroll
    for (int mt = 0; mt < 2; mt++) {
        int lbase = mt * 64 + wave * 16;
        size_t gbase = (size_t)((mt == 0 ? n0 : HW + n0) + wave * 16);
        bf16x8 a[2];
#pragma unroll
        for (int ks = 0; ks < 2; ks++)
            a[ks] = *reinterpret_cast<const bf16x8*>(
                &Q[(lbase + lm) * 200 + ks * 32 + quad * 8]);
        f32x4 acc[4] = {};
#pragma unroll
        for (int nt = 0; nt < 4; nt++)
#pragma unroll
            for (int ks = 0; ks < 2; ks++) {
                bf16x8 b = ldg8(Wo + (size_t)(nt * 16 + lm) * 64 + ks * 32 + quad * 8);
                acc[nt] = __builtin_amdgcn_mfma_f32_16x16x32_bf16(a[ks], b, acc[nt], 0, 0, 0);
            }

        float bv[4], gv[4], bev[4];
#pragma unroll
        for (int nt = 0; nt < 4; nt++) {
            bv[nt]  = Bo[nt * 16 + lm];
            gv[nt]  = g[nt * 16 + lm];
            bev[nt] = be[nt * 16 + lm];
        }
#pragma unroll
        for (int r = 0; r < 4; r++) {
            size_t row = gbase + quad * 4 + r;
            float v[4]; float s = 0.f;
#pragma unroll
            for (int nt = 0; nt < 4; nt++) {
                v[nt] = acc[nt][r] + bv[nt] + bf2f(Tb[row * 64 + nt * 16 + lm]);
                s += v[nt];
            }
#pragma unroll
            for (int o = 8; o; o >>= 1) s += __shfl_xor(s, o, 64);
            float mu = s * 0.015625f;
            float q = 0.f;
#pragma unroll
            for (int nt = 0; nt < 4; nt++) { v[nt] -= mu; q += v[nt] * v[nt]; }
#pragma unroll
            for (int o = 8; o; o >>= 1) q += __shfl_xor(q, o, 64);
            float rstd = rsqrtf(q * 0.015625f + 1e-5f);
#pragma unroll
            for (int nt = 0; nt < 4; nt++)
                T1b[row * 64 + nt * 16 + lm] = f2bf(gv[nt] * v[nt] * rstd + bev[nt]);
        }
    }
}

// ---------------------------------------------------------------------------
// FFN v6: LDS-staged weights (as v5) + bias-initialized phase1 accumulators,
// packed f16 conversion, and paired-K phase2 via mfma_f32_16x16x32_f16.
// mt=2 (32 rows/wave, 128/block, 784 blocks). Fused bf16 residual + LN2.
// ---------------------------------------------------------------------------
__global__ __launch_bounds__(256) void ffn6_k(
    const ushort_t* __restrict__ T1b,
    const ushort_t* __restrict__ W1p, const float* __restrict__ B1,
    const _Float16* __restrict__ W2s, const float* __restrict__ B2,
    const float* __restrict__ g, const float* __restrict__ be,
    ushort_t* __restrict__ OutTb)
{
    __shared__ ushort_t W1lds[2][6144];   // rows stride 72 bf16, 12288 B each
    __shared__ ushort_t W2lds[2][4096];   // f16 bits, 8192 B each

    int tid = threadIdx.x, wave = tid >> 6, lane = tid & 63;
    int lm = lane & 15, quad = lane >> 4;
    int rowbase = blockIdx.x * 128 + wave * 32;

    bf16x8 Bt[2][2];
#pragma unroll
    for (int mt = 0; mt < 2; mt++)
#pragma unroll
        for (int ks = 0; ks < 2; ks++)
            Bt[mt][ks] = ldg8(T1b + (size_t)(rowbase + mt * 16 + lm) * 64 + ks * 32 + quad * 8);

    f32x4 acc[2][4] = {};

    auto dma_chunk = [&](int c, int pb) {
        const ushort_t* g1 = W1p + (size_t)c * 6144;
#pragma unroll
        for (int r = 0; r < 3; r++)
            dma16(g1 + (r * 4 + wave) * 512 + lane * 8,
                  &W1lds[pb][(r * 4 + wave) * 512]);
        const ushort_t* g2 = (const ushort_t*)(W2s + (size_t)c * 4096);
#pragma unroll
        for (int r = 0; r < 2; r++)
            dma16(g2 + (r * 4 + wave) * 512 + lane * 8,
                  &W2lds[pb][(r * 4 + wave) * 512]);
    };

    dma_chunk(0, 0);

    for (int c = 0; c < 32; c++) {
        int pb = c & 1;
        __syncthreads();                    // drains chunk-c DMA; syncs buffer reuse
        if (c + 1 < 32) dma_chunk(c + 1, pb ^ 1);

        const ushort_t* w1l = &W1lds[pb][0];
        const ushort_t* w2l = &W2lds[pb][0];

#pragma unroll
        for (int p = 0; p < 2; p++) {
            bf16x8 w1r[2][2];
            f16x8  w2r[4];
            float4 b1r[2];
#pragma unroll
            for (int s = 0; s < 2; s++) {
                int ul = p * 2 + s;
#pragma unroll
                for (int ks = 0; ks < 2; ks++)
                    w1r[s][ks] = *reinterpret_cast<const bf16x8*>(
                        &w1l[(ul * 16 + lm) * 72 + ks * 32 + quad * 8]);
                b1r[s] = *reinterpret_cast<const float4*>(B1 + (c * 4 + ul) * 16 + quad * 4);
            }
#pragma unroll
            for (int nt = 0; nt < 4; nt++)
                w2r[nt] = *reinterpret_cast<const f16x8*>(
                    &w2l[((p * 4 + nt) * 64 + lane) * 8]);

            // phase 1: bias-initialized accumulators
            f32x4 h[2][2];
#pragma unroll
            for (int s = 0; s < 2; s++) {
                f32x4 binit = {b1r[s].x, b1r[s].y, b1r[s].z, b1r[s].w};
#pragma unroll
                for (int mt = 0; mt < 2; mt++) h[s][mt] = binit;
            }
#pragma unroll
            for (int s = 0; s < 2; s++)
#pragma unroll
                for (int ks = 0; ks < 2; ks++)
#pragma unroll
                    for (int mt = 0; mt < 2; mt++)
                        h[s][mt] = __builtin_amdgcn_mfma_f32_16x16x32_bf16(
                            w1r[s][ks], Bt[mt][ks], h[s][mt], 0, 0, 0);

            // relu + packed cvt -> paired-K A fragment (j0..3 = ul0, j4..7 = ul1)
            f16x8 aH[2];
#pragma unroll
            for (int mt = 0; mt < 2; mt++) {
                f16x2 t0 = pk16(fmaxf(h[0][mt][0], 0.f), fmaxf(h[0][mt][1], 0.f));
                f16x2 t1 = pk16(fmaxf(h[0][mt][2], 0.f), fmaxf(h[0][mt][3], 0.f));
                f16x2 t2 = pk16(fmaxf(h[1][mt][0], 0.f), fmaxf(h[1][mt][1], 0.f));
                f16x2 t3 = pk16(fmaxf(h[1][mt][2], 0.f), fmaxf(h[1][mt][3], 0.f));
                f16x8 a;
                a[0] = t0[0]; a[1] = t0[1]; a[2] = t1[0]; a[3] = t1[1];
                a[4] = t2[0]; a[5] = t2[1]; a[6] = t3[0]; a[7] = t3[1];
                aH[mt] = a;
            }

            // phase 2: paired-K f16 MFMA
#pragma unroll
            for (int nt = 0; nt < 4; nt++)
#pragma unroll
                for (int mt = 0; mt < 2; mt++)
                    acc[mt][nt] = __builtin_amdgcn_mfma_f32_16x16x32_f16(
                        aH[mt], w2r[nt], acc[mt][nt], 0, 0, 0);
        }
    }

    // ---- epilogue: + b2 + residual(t1 bf16) -> LN2 -> bf16 ----
    float b2v[4], gv[4], bev[4];
#pragma unroll
    for (int nt = 0; nt < 4; nt++) {
        b2v[nt] = B2[nt * 16 + lm];
        gv[nt]  = g[nt * 16 + lm];
        bev[nt] = be[nt * 16 + lm];
    }
#pragma unroll
    for (int mt = 0; mt < 2; mt++)
#pragma unroll
        for (int r = 0; r < 4; r++) {
            int row = rowbase + mt * 16 + quad * 4 + r;
            float v[4]; float s = 0.f;
#pragma unroll
            for (int nt = 0; nt < 4; nt++) {
                v[nt] = acc[mt][nt][r] + b2v[nt] +
                        bf2f(T1b[(size_t)row * 64 + nt * 16 + lm]);
                s += v[nt];
            }
#pragma unroll
            for (int o = 8; o; o >>= 1) s += __shfl_xor(s, o, 64);
            float mu = s * 0.015625f;
            float q = 0.f;
#pragma unroll
            for (int nt = 0; nt < 4; nt++) { v[nt] -= mu; q += v[nt] * v[nt]; }
#pragma unroll
            for (int o = 8; o; o >>= 1) q += __shfl_xor(q, o, 64);
            float rstd = rsqrtf(q * 0.015625f + 1e-5f);
#pragma unroll
            for (int nt = 0; nt < 4; nt++)
                OutTb[(size_t)row * 64 + nt * 16 + lm] =
                    f2bf(gv[nt] * v[nt] * rstd + bev[nt]);
        }
}

// ---------------------------------------------------------------------------
__global__ __launch_bounds__(256) void ssum_k(const float* __restrict__ x,
                                              float* __restrict__ s)
{
    int gid = blockIdx.x * 256 + threadIdx.x;
    int b = gid / HW;
    int p = gid - b * HW;
    const float* xp = x + (size_t)b * 3 * HW + p;
    s[gid] = xp[0] + xp[HW] + xp[2 * HW];
}

// KPN fuse; filters in NE-padded layout [pix][16] (taps 0..8 valid)
__global__ __launch_bounds__(256) void kpn_k(const float* __restrict__ f,
                                             const float* __restrict__ s,
                                             float* __restrict__ out)
{
    int gid = blockIdx.x * 256 + threadIdx.x;
    int b = gid / HW;
    int p = gid - b * HW;
    int y = p / IW, x = p - y * IW;
    const float* fp = f + (size_t)gid * 16;
    const float* sp = s + (size_t)b * HW;
    float acc = 0.f;
#pragma unroll
    for (int u = 0; u < 3; u++) {
        int yy = y + u - 1;
        if ((unsigned)yy >= (unsigned)IW) continue;
#pragma unroll
        for (int v = 0; v < 3; v++) {
            int xx = x + v - 1;
            if ((unsigned)xx >= (unsigned)IW) continue;
            acc += fp[u * 3 + v] * sp[yy * IW + xx];
        }
    }
    out[gid] = acc;
}

// ---------------------------------------------------------------------------
// dec1: 1->64 conv, per-pixel thread, taps read once, NE bf16 out, relu
// ---------------------------------------------------------------------------
__global__ __launch_bounds__(256) void dec1_ne_k(const float* __restrict__ fused,
                                                 const float* __restrict__ w,
                                                 const float* __restrict__ bias,
                                                 ushort_t* __restrict__ out)
{
    int gid = blockIdx.x * 256 + threadIdx.x;  // < NPIX
    int b = gid >= HW;
    int p = gid - b * HW;
    int y = p / IW, xx = p - y * IW;
    const float* ip = fused + (size_t)b * HW;

    float v[9];
#pragma unroll
    for (int t = 0; t < 9; t++) {
        int yy = y + t / 3 - 1, xc = xx + t % 3 - 1;
        float tv = 0.f;
        if ((unsigned)yy < (unsigned)IW && (unsigned)xc < (unsigned)IW)
            tv = ip[yy * IW + xc];
        v[t] = tv;
    }
#pragma unroll
    for (int g = 0; g < 8; g++) {
        ushort8 o8;
#pragma unroll
        for (int i = 0; i < 8; i++) {
            int co = g * 8 + i;
            float a = bias[co];
            const float* wp = w + co * 9;
#pragma unroll
            for (int t = 0; t < 9; t++) a = fmaf(v[t], wp[t], a);
            o8[i] = f2bf(fmaxf(a, 0.f));
        }
        *reinterpret_cast<ushort8*>(out + (size_t)gid * 64 + g * 8) = o8;
    }
}

// ---------------------------------------------------------------------------
// dec2: 64->1 conv over NE bf16 input, sigmoid, fp32 out
// ---------------------------------------------------------------------------
__global__ __launch_bounds__(256) void dec2_ne_k(const ushort_t* __restrict__ D1,
                                                 const float* __restrict__ w,
                                                 const float* __restrict__ bias,
                                                 float* __restrict__ out)
{
    int gid = blockIdx.x * 256 + threadIdx.x;  // < NPIX
    int b = gid >= HW;
    int p = gid - b * HW;
    int y = p / IW, xx = p - y * IW;

    float acc = bias[0];
#pragma unroll
    for (int t = 0; t < 9; t++) {
        int yy = y + t / 3 - 1, xc = xx + t % 3 - 1;
        if ((unsigned)yy >= (unsigned)IW || (unsigned)xc >= (unsigned)IW) continue;
        const ushort_t* ip = D1 + (size_t)(gid + (t / 3 - 1) * IW + (t % 3 - 1)) * 64;
#pragma unroll
        for (int ks = 0; ks < 8; ks++) {
            float fv[8];
            b2f8(ip + ks * 8, fv);
#pragma unroll
            for (int i = 0; i < 8; i++)
                acc = fmaf(fv[i], w[(ks * 8 + i) * 9 + t], acc);
        }
    }
    out[gid] = 1.f / (1.f + __expf(-acc));
}

// ---------------------------------------------------------------------------
extern "C" void kernel_launch(void* const* d_in, const int* in_sizes, int n_in,
                              void* d_out, int out_size, void* d_ws, size_t ws_size,
                              hipStream_t stream)
{
    const float* x      = (const float*)d_in[0];
    const float* enc_w1 = (const float*)d_in[1];
    const float* enc_b1 = (const float*)d_in[2];
    const float* enc_w2 = (const float*)d_in[3];
    const float* enc_b2 = (const float*)d_in[4];
    const float* in_w   = (const float*)d_in[5];
    const float* in_b   = (const float*)d_in[6];
    const float* out_w  = (const float*)d_in[7];
    const float* out_b  = (const float*)d_in[8];
    const float* ln1_g  = (const float*)d_in[9];
    const float* ln1_b  = (const float*)d_in[10];
    const float* ffn_w1 = (const float*)d_in[11];
    const float* ffn_b1 = (const float*)d_in[12];
    const float* ffn_w2 = (const float*)d_in[13];
    const float* ffn_b2 = (const float*)d_in[14];
    const float* ln2_g  = (const float*)d_in[15];
    const float* ln2_b  = (const float*)d_in[16];
    const float* sf_w1  = (const float*)d_in[17];
    const float* sf_b1  = (const float*)d_in[18];
    const float* sf_w2  = (const float*)d_in[19];
    const float* sf_b2  = (const float*)d_in[20];
    const float* dec_w1 = (const float*)d_in[21];
    const float* dec_b1 = (const float*)d_in[22];
    const float* dec_w2 = (const float*)d_in[23];
    const float* dec_b2 = (const float*)d_in[24];

    float* ws = (float*)d_ws;
    const size_t SZ = (size_t)NPIX * 64;

    ushort_t* E1b  = (ushort_t*)(ws + 5 * SZ);             // conv1 out / t1 bf16
    ushort_t* Tb   = (ushort_t*)(ws + 11 * SZ / 2);        // conv2 bf16 / t2 bf16
    ushort_t* wu   = (ushort_t*)(ws + 6 * SZ);             // weights
    ushort_t* in_wb  = wu;                                 // 12288
    ushort_t* out_wb = wu + 12288;                         // 4096
    ushort_t* w1p    = wu + 16384;                         // 196608 (padded chunks)
    _Float16* w2s    = (_Float16*)(wu + 212992);           // 131072 halves
    ushort_t* wc2    = wu + 344064;                        // 36864
    ushort_t* ws1    = wu + 380928;                        // 18432
    ushort_t* ws2    = wu + 399360;                        // 4608
    // late-stage scratch:
    float*    base3 = ws + 3 * SZ;
    ushort_t* s1b   = (ushort_t*)base3;                    // NPIX*32 bf16 (SZ/4 floats)
    float*    filtp = base3 + SZ / 4;                      // NPIX*16 f32 (SZ/4)
    float*    sbuf  = base3 + SZ / 2;                      // NPIX
    float*    fused = sbuf + NPIX;                         // NPIX
    ushort_t* D1b   = (ushort_t*)(base3 + SZ / 2 + 2 * (size_t)NPIX);  // NPIX*64 bf16

    // ---- merged weight prep ----
    prep_k<<<1322, 256, 0, stream>>>(in_w, in_wb, out_w, out_wb, ffn_w1, w1p,
                                     ffn_w2, w2s, enc_w2, wc2, sf_w1, ws1, sf_w2, ws2);

    // ---- encoder ----
    conv1_ne_k<<<392, 256, 0, stream>>>(x, enc_w1, enc_b1, E1b);
    neconv_k<2, 4, 64, 1, false, true><<<784, 256, 0, stream>>>(E1b, wc2, enc_b2, nullptr, Tb);
    // ---- transformer (fused qkv+attn+oproj+LN1) ----
    xformer_k<<<784, 256, 0, stream>>>(Tb, in_wb, in_b, out_wb, out_b,
                                       ln1_g, ln1_b, E1b);
    ffn6_k<<<784, 256, 0, stream>>>(E1b, w1p, ffn_b1, w2s, ffn_b2, ln2_g, ln2_b, Tb);
    // ---- filter prediction ----
    neconv_k<2, 2, 32, 0, false, true><<<784, 256, 0, stream>>>(Tb, ws1, sf_b1, nullptr, s1b);
    neconv_k<1, 1, 9, 0, true, false><<<784, 256, 0, stream>>>(s1b, ws2, sf_b2, filtp, nullptr);
    // ---- KPN fuse ----
    ssum_k<<<392, 256, 0, stream>>>(x, sbuf);
    kpn_k<<<392, 256, 0, stream>>>(filtp, sbuf, fused);
    // ---- decoder (NE) ----
    dec1_ne_k<<<392, 256, 0, stream>>>(fused, dec_w1, dec_b1, D1b);
    dec2_ne_k<<<392, 256, 0, stream>>>(D1b, dec_w2, dec_b2, (float*)d_out);
}